// Round 1
// baseline (1857.596 us; speedup 1.0000x reference)
//
#include <hip/hip_runtime.h>
#include <cmath>

#define DIMM 1024
#define NHEADS 16
#define NKV 4
#define HD 64
#define SEQ 1024
#define BSZ 8
#define ROWS (BSZ * SEQ)   // 8192

// ---------------- weight abs-mean partial reduce ----------------
__global__ __launch_bounds__(256) void k_absmean(const float* __restrict__ w, int n,
                                                 float* __restrict__ partial) {
    float s = 0.f;
    for (int i = blockIdx.x * 256 + threadIdx.x; i < n; i += 64 * 256) s += fabsf(w[i]);
    #pragma unroll
    for (int off = 32; off; off >>= 1) s += __shfl_xor(s, off);
    __shared__ float red[4];
    if ((threadIdx.x & 63) == 0) red[threadIdx.x >> 6] = s;
    __syncthreads();
    if (threadIdx.x == 0) partial[blockIdx.x] = red[0] + red[1] + red[2] + red[3];
}

// ---------------- alpha = max(mean|w|, eps) for the 4 weights ----------------
__global__ void k_alpha(const float* __restrict__ partial, float* __restrict__ alpha) {
    int i = threadIdx.x;
    if (i < 4) {
        const int ns[4] = {1048576, 262144, 262144, 1048576};
        float s = 0.f;
        for (int j = 0; j < 64; ++j) s += partial[i * 64 + j];
        alpha[i] = fmaxf(s / (float)ns[i], 1e-8f);
    }
}

// ---------------- ternarize: wt = round(clip(w/alpha,-1,1)) ----------------
__global__ __launch_bounds__(256) void k_tern(const float* __restrict__ w,
                                              const float* __restrict__ alpha, int ai,
                                              float* __restrict__ wt, int n) {
    float a = alpha[ai];
    for (int i = blockIdx.x * blockDim.x + threadIdx.x; i < n; i += gridDim.x * blockDim.x)
        wt[i] = rintf(fminf(fmaxf(w[i] / a, -1.f), 1.f));
}

// ---------------- per-row activation quantization ----------------
__global__ __launch_bounds__(256) void k_quant(const float* __restrict__ X,
                                               float* __restrict__ Xq, float* __restrict__ g) {
    int row = blockIdx.x;
    const float* xr = X + (size_t)row * DIMM;
    float v[4];
    float mv = 0.f;
    #pragma unroll
    for (int i = 0; i < 4; ++i) {
        v[i] = xr[threadIdx.x + i * 256];
        mv = fmaxf(mv, fabsf(v[i]));
    }
    #pragma unroll
    for (int off = 32; off; off >>= 1) mv = fmaxf(mv, __shfl_xor(mv, off));
    __shared__ float red[4];
    if ((threadIdx.x & 63) == 0) red[threadIdx.x >> 6] = mv;
    __syncthreads();
    mv = fmaxf(fmaxf(red[0], red[1]), fmaxf(red[2], red[3]));
    float gamma = fmaxf(mv, 1e-8f) / 127.0f;
    float* xo = Xq + (size_t)row * DIMM;
    #pragma unroll
    for (int i = 0; i < 4; ++i)
        xo[threadIdx.x + i * 256] = rintf(fminf(fmaxf(v[i] / gamma, -128.f), 127.f));
    if (threadIdx.x == 0) g[row] = gamma;
}

// ---------------- tiled GEMM: C[r][c] = (A[r,:]·B[c,:]) * gamma[r]*alpha ----------------
// A: ROWS x 1024, B: cols x 1024 (both contain small integers stored as f32 -> exact fp32 FMA)
__global__ __launch_bounds__(256) void k_gemm64(const float* __restrict__ A,
                                                const float* __restrict__ B,
                                                const float* __restrict__ gamma,
                                                const float* __restrict__ alpha_p, int ai,
                                                float* __restrict__ C, int cols) {
    __shared__ float As[64][68];  // [k][row]
    __shared__ float Bs[64][68];  // [k][col]
    const int K = DIMM;
    int tid = threadIdx.x;
    int row0 = blockIdx.y * 64;
    int col0 = blockIdx.x * 64;
    int ty = tid >> 4, tx = tid & 15;
    float acc[4][4] = {{0.f}};
    for (int k0 = 0; k0 < K; k0 += 64) {
        #pragma unroll
        for (int i = 0; i < 4; ++i) {
            int li = tid + i * 256;
            int r = li >> 4;   // 0..63
            int c4 = li & 15;  // 0..15
            float4 av = *reinterpret_cast<const float4*>(&A[(size_t)(row0 + r) * K + k0 + c4 * 4]);
            As[c4 * 4 + 0][r] = av.x; As[c4 * 4 + 1][r] = av.y;
            As[c4 * 4 + 2][r] = av.z; As[c4 * 4 + 3][r] = av.w;
            float4 bv = *reinterpret_cast<const float4*>(&B[(size_t)(col0 + r) * K + k0 + c4 * 4]);
            Bs[c4 * 4 + 0][r] = bv.x; Bs[c4 * 4 + 1][r] = bv.y;
            Bs[c4 * 4 + 2][r] = bv.z; Bs[c4 * 4 + 3][r] = bv.w;
        }
        __syncthreads();
        #pragma unroll 8
        for (int k = 0; k < 64; ++k) {
            float4 a4 = *reinterpret_cast<const float4*>(&As[k][ty * 4]);
            float4 b4 = *reinterpret_cast<const float4*>(&Bs[k][tx * 4]);
            float a[4] = {a4.x, a4.y, a4.z, a4.w};
            float b[4] = {b4.x, b4.y, b4.z, b4.w};
            #pragma unroll
            for (int i = 0; i < 4; ++i)
                #pragma unroll
                for (int j = 0; j < 4; ++j) acc[i][j] += a[i] * b[j];
        }
        __syncthreads();
    }
    float alpha = alpha_p[ai];
    #pragma unroll
    for (int i = 0; i < 4; ++i) {
        int r = row0 + ty * 4 + i;
        float sc = gamma[r] * alpha;
        float4 o;
        o.x = acc[i][0] * sc; o.y = acc[i][1] * sc;
        o.z = acc[i][2] * sc; o.w = acc[i][3] * sc;
        *reinterpret_cast<float4*>(&C[(size_t)r * cols + col0 + tx * 4]) = o;
    }
}

// ---------------- rope table ----------------
__global__ __launch_bounds__(256) void k_rope(float* __restrict__ c, float* __restrict__ s) {
    int idx = blockIdx.x * 256 + threadIdx.x;  // < 32768
    int t = idx >> 5, i = idx & 31;
    float inv = 1.0f / powf(10000.0f, (float)(2 * i) * (1.0f / 64.0f));
    float f = (float)t * inv;
    c[idx] = cosf(f);
    s[idx] = sinf(f);
}

// ---------------- q prep: rms_norm + rope + gain, layout -> [b,h,s,d] ----------------
__global__ __launch_bounds__(256) void k_prep_q(const float* __restrict__ C,
                                                const float* __restrict__ rc,
                                                const float* __restrict__ rs,
                                                const float* __restrict__ gain,
                                                float* __restrict__ Qo) {
    int lane = threadIdx.x & 63;
    int task = blockIdx.x * 4 + (threadIdx.x >> 6);  // (b*16+h)*1024+s
    int s = task & 1023;
    int h = (task >> 10) & 15;
    int b = task >> 14;
    float xv = C[(((size_t)b * 1024 + s) * 16 + h) * 64 + lane];
    float ss = xv * xv;
    #pragma unroll
    for (int off = 32; off; off >>= 1) ss += __shfl_xor(ss, off);
    float r = 1.0f / sqrtf(ss * (1.0f / 64.0f) + 1.1920929e-07f);
    xv *= r;
    float xp = __shfl_xor(xv, 32);
    int i = lane & 31;
    float c = rc[s * 32 + i], sn = rs[s * 32 + i];
    float y = (lane < 32) ? (xv * c + xp * sn) : (xv * c - xp * sn);
    y *= gain[h];
    Qo[(size_t)task * 64 + lane] = y;
}

// ---------------- k prep: rms_norm + rope, layout -> [b,kv,s,d] ----------------
__global__ __launch_bounds__(256) void k_prep_k(const float* __restrict__ C,
                                                const float* __restrict__ rc,
                                                const float* __restrict__ rs,
                                                float* __restrict__ Ko) {
    int lane = threadIdx.x & 63;
    int task = blockIdx.x * 4 + (threadIdx.x >> 6);  // (b*4+kv)*1024+s
    int s = task & 1023;
    int kv = (task >> 10) & 3;
    int b = task >> 12;
    float xv = C[(((size_t)b * 1024 + s) * 4 + kv) * 64 + lane];
    float ss = xv * xv;
    #pragma unroll
    for (int off = 32; off; off >>= 1) ss += __shfl_xor(ss, off);
    float r = 1.0f / sqrtf(ss * (1.0f / 64.0f) + 1.1920929e-07f);
    xv *= r;
    float xp = __shfl_xor(xv, 32);
    int i = lane & 31;
    float c = rc[s * 32 + i], sn = rs[s * 32 + i];
    float y = (lane < 32) ? (xv * c + xp * sn) : (xv * c - xp * sn);
    Ko[(size_t)task * 64 + lane] = y;
}

// ---------------- v transpose: [b,s,kv,d] -> [b,kv,s,d] ----------------
__global__ __launch_bounds__(256) void k_vtrans(const float* __restrict__ Cv,
                                                float* __restrict__ Vo) {
    int idx = blockIdx.x * 256 + threadIdx.x;  // over 524288 float4s
    int d4 = idx & 15;
    int rest = idx >> 4;  // b*4096 + kv*1024 + s
    int s = rest & 1023;
    int kv = (rest >> 10) & 3;
    int b = rest >> 12;
    float4 v = *reinterpret_cast<const float4*>(
        &Cv[((((size_t)b * 1024 + s) * 4 + kv) * 64) + d4 * 4]);
    *reinterpret_cast<float4*>(&Vo[((((size_t)b * 4 + kv) * 1024 + s) * 64) + d4 * 4]) = v;
}

// ---------------- causal flash attention ----------------
// grid (S/64, H, B); 4 waves; wave handles 16 q rows; 4 lanes per row (16 dims each)
__global__ __launch_bounds__(256) void k_attn(const float* __restrict__ Q,
                                              const float* __restrict__ Kk,
                                              const float* __restrict__ V,
                                              float* __restrict__ Y) {
    __shared__ float Kt[64][68];
    __shared__ float Vt[64][68];
    int qt = blockIdx.x, h = blockIdx.y, b = blockIdx.z;
    int kvh = h >> 2;
    int wave = threadIdx.x >> 6, lane = threadIdx.x & 63;
    int rl = lane >> 2, part = lane & 3;
    int qrow = qt * 64 + wave * 16 + rl;
    const float* qp = Q + ((((size_t)b * 16 + h) * 1024) + qrow) * 64 + part * 16;
    float qr[16];
    #pragma unroll
    for (int d = 0; d < 16; ++d) qr[d] = qp[d];
    float o[16];
    #pragma unroll
    for (int d = 0; d < 16; ++d) o[d] = 0.f;
    float m = -INFINITY, l = 0.f;
    const float* kbase = Kk + (((size_t)b * 4 + kvh) * 1024) * 64;
    const float* vbase = V + (((size_t)b * 4 + kvh) * 1024) * 64;
    for (int t = 0; t <= qt; ++t) {
        int k0 = t * 64;
        #pragma unroll
        for (int i = 0; i < 4; ++i) {
            int li = threadIdx.x + i * 256;
            int r = li >> 4, c4 = li & 15;
            *reinterpret_cast<float4*>(&Kt[r][c4 * 4]) =
                *reinterpret_cast<const float4*>(&kbase[(size_t)(k0 + r) * 64 + c4 * 4]);
            *reinterpret_cast<float4*>(&Vt[r][c4 * 4]) =
                *reinterpret_cast<const float4*>(&vbase[(size_t)(k0 + r) * 64 + c4 * 4]);
        }
        __syncthreads();
        int jmax = qrow - k0 + 1;
        if (jmax > 64) jmax = 64;
        for (int j = 0; j < 64; ++j) {
            float s = 0.f;
            #pragma unroll
            for (int d4 = 0; d4 < 4; ++d4) {
                float4 kk = *reinterpret_cast<const float4*>(&Kt[j][part * 16 + d4 * 4]);
                s += qr[d4 * 4 + 0] * kk.x + qr[d4 * 4 + 1] * kk.y +
                     qr[d4 * 4 + 2] * kk.z + qr[d4 * 4 + 3] * kk.w;
            }
            s += __shfl_xor(s, 1);
            s += __shfl_xor(s, 2);
            s *= 0.125f;
            if (j < jmax) {
                float mn = fmaxf(m, s);
                float corr = expf(m - mn);
                float p = expf(s - mn);
                l = l * corr + p;
                #pragma unroll
                for (int d4 = 0; d4 < 4; ++d4) {
                    float4 vv = *reinterpret_cast<const float4*>(&Vt[j][part * 16 + d4 * 4]);
                    o[d4 * 4 + 0] = o[d4 * 4 + 0] * corr + p * vv.x;
                    o[d4 * 4 + 1] = o[d4 * 4 + 1] * corr + p * vv.y;
                    o[d4 * 4 + 2] = o[d4 * 4 + 2] * corr + p * vv.z;
                    o[d4 * 4 + 3] = o[d4 * 4 + 3] * corr + p * vv.w;
                }
                m = mn;
            }
        }
        __syncthreads();
    }
    float inv = 1.0f / l;
    float* yp = Y + (((size_t)b * 1024) + qrow) * 1024 + h * 64 + part * 16;
    #pragma unroll
    for (int d4 = 0; d4 < 4; ++d4) {
        float4 ov;
        ov.x = o[d4 * 4 + 0] * inv; ov.y = o[d4 * 4 + 1] * inv;
        ov.z = o[d4 * 4 + 2] * inv; ov.w = o[d4 * 4 + 3] * inv;
        *reinterpret_cast<float4*>(&yp[d4 * 4]) = ov;
    }
}

extern "C" void kernel_launch(void* const* d_in, const int* in_sizes, int n_in,
                              void* d_out, int out_size, void* d_ws, size_t ws_size,
                              hipStream_t stream) {
    (void)in_sizes; (void)n_in; (void)out_size; (void)ws_size;
    const float* x  = (const float*)d_in[0];
    const float* Wq = (const float*)d_in[1];
    const float* Wk = (const float*)d_in[2];
    const float* Wv = (const float*)d_in[3];
    const float* Wp = (const float*)d_in[4];
    const float* qg = (const float*)d_in[5];
    float* out = (float*)d_out;

    float* p = (float*)d_ws;
    float* partial = p; p += 256;
    float* alpha = p;   p += 16;
    float* wtq = p; p += 1048576;
    float* wtk = p; p += 262144;
    float* wtv = p; p += 262144;
    float* wtp = p; p += 1048576;
    float* xq  = p; p += 8388608;
    float* gam = p; p += 8192;
    float* cq  = p; p += 8388608;
    float* ck  = p; p += 2097152;
    float* cv  = p; p += 2097152;
    float* qo  = p; p += 8388608;
    float* ko  = p; p += 2097152;
    float* vo  = p; p += 2097152;
    float* rc  = p; p += 32768;
    float* rs  = p; p += 32768;
    float* y   = cq;   // reuse (cq dead after prep_q)
    float* yq  = xq;   // reuse (xq dead after qkv gemms)

    // weight quantization
    k_absmean<<<64, 256, 0, stream>>>(Wq, 1048576, partial + 0);
    k_absmean<<<64, 256, 0, stream>>>(Wk, 262144, partial + 64);
    k_absmean<<<64, 256, 0, stream>>>(Wv, 262144, partial + 128);
    k_absmean<<<64, 256, 0, stream>>>(Wp, 1048576, partial + 192);
    k_alpha<<<1, 64, 0, stream>>>(partial, alpha);
    k_tern<<<1024, 256, 0, stream>>>(Wq, alpha, 0, wtq, 1048576);
    k_tern<<<256, 256, 0, stream>>>(Wk, alpha, 1, wtk, 262144);
    k_tern<<<256, 256, 0, stream>>>(Wv, alpha, 2, wtv, 262144);
    k_tern<<<1024, 256, 0, stream>>>(Wp, alpha, 3, wtp, 1048576);

    // rope table
    k_rope<<<128, 256, 0, stream>>>(rc, rs);

    // activation quantization + projections
    k_quant<<<ROWS, 256, 0, stream>>>(x, xq, gam);
    k_gemm64<<<dim3(16, 128), 256, 0, stream>>>(xq, wtq, gam, alpha, 0, cq, 1024);
    k_gemm64<<<dim3(4, 128), 256, 0, stream>>>(xq, wtk, gam, alpha, 1, ck, 256);
    k_gemm64<<<dim3(4, 128), 256, 0, stream>>>(xq, wtv, gam, alpha, 2, cv, 256);

    // norm + rope + layout
    k_prep_q<<<32768, 256, 0, stream>>>(cq, rc, rs, qg, qo);
    k_prep_k<<<8192, 256, 0, stream>>>(ck, rc, rs, ko);
    k_vtrans<<<2048, 256, 0, stream>>>(cv, vo);

    // attention
    k_attn<<<dim3(16, 16, 8), 256, 0, stream>>>(qo, ko, vo, y);

    // output projection
    k_quant<<<ROWS, 256, 0, stream>>>(y, yq, gam);
    k_gemm64<<<dim3(16, 128), 256, 0, stream>>>(yq, wtp, gam, alpha, 3, out, 1024);
}

// Round 2
// 918.611 us; speedup vs baseline: 2.0222x; 2.0222x over previous
//
#include <hip/hip_runtime.h>
#include <cmath>

#define DIMM 1024
#define NHEADS 16
#define NKV 4
#define HD 64
#define SEQ 1024
#define BSZ 8
#define ROWS (BSZ * SEQ)   // 8192

typedef unsigned short u16;
typedef __attribute__((ext_vector_type(8))) short bf16x8;
typedef __attribute__((ext_vector_type(4))) float f32x4;

static __device__ __forceinline__ u16 f2bf(float f) {
    union { float f; unsigned u; } v; v.f = f;
    unsigned r = v.u + 0x7FFFu + ((v.u >> 16) & 1u);
    return (u16)(r >> 16);
}

// ---------------- weight abs-mean partial reduce ----------------
__global__ __launch_bounds__(256) void k_absmean(const float* __restrict__ w, int n,
                                                 float* __restrict__ partial) {
    float s = 0.f;
    for (int i = blockIdx.x * 256 + threadIdx.x; i < n; i += 64 * 256) s += fabsf(w[i]);
    #pragma unroll
    for (int off = 32; off; off >>= 1) s += __shfl_xor(s, off);
    __shared__ float red[4];
    if ((threadIdx.x & 63) == 0) red[threadIdx.x >> 6] = s;
    __syncthreads();
    if (threadIdx.x == 0) partial[blockIdx.x] = red[0] + red[1] + red[2] + red[3];
}

// ---------------- alpha = max(mean|w|, eps) for the 4 weights ----------------
__global__ void k_alpha(const float* __restrict__ partial, float* __restrict__ alpha) {
    int i = threadIdx.x;
    if (i < 4) {
        const int ns[4] = {1048576, 262144, 262144, 1048576};
        float s = 0.f;
        for (int j = 0; j < 64; ++j) s += partial[i * 64 + j];
        alpha[i] = fmaxf(s / (float)ns[i], 1e-8f);
    }
}

// ---------------- ternarize: wt = round(clip(w/alpha,-1,1)) ----------------
__global__ __launch_bounds__(256) void k_tern(const float* __restrict__ w,
                                              const float* __restrict__ alpha, int ai,
                                              float* __restrict__ wt, int n) {
    float a = alpha[ai];
    for (int i = blockIdx.x * blockDim.x + threadIdx.x; i < n; i += gridDim.x * blockDim.x)
        wt[i] = rintf(fminf(fmaxf(w[i] / a, -1.f), 1.f));
}

// ---------------- per-row activation quantization ----------------
__global__ __launch_bounds__(256) void k_quant(const float* __restrict__ X,
                                               float* __restrict__ Xq, float* __restrict__ g) {
    int row = blockIdx.x;
    const float* xr = X + (size_t)row * DIMM;
    float v[4];
    float mv = 0.f;
    #pragma unroll
    for (int i = 0; i < 4; ++i) {
        v[i] = xr[threadIdx.x + i * 256];
        mv = fmaxf(mv, fabsf(v[i]));
    }
    #pragma unroll
    for (int off = 32; off; off >>= 1) mv = fmaxf(mv, __shfl_xor(mv, off));
    __shared__ float red[4];
    if ((threadIdx.x & 63) == 0) red[threadIdx.x >> 6] = mv;
    __syncthreads();
    mv = fmaxf(fmaxf(red[0], red[1]), fmaxf(red[2], red[3]));
    float gamma = fmaxf(mv, 1e-8f) / 127.0f;
    float* xo = Xq + (size_t)row * DIMM;
    #pragma unroll
    for (int i = 0; i < 4; ++i)
        xo[threadIdx.x + i * 256] = rintf(fminf(fmaxf(v[i] / gamma, -128.f), 127.f));
    if (threadIdx.x == 0) g[row] = gamma;
}

// ---------------- tiled GEMM: C[r][c] = (A[r,:]·B[c,:]) * gamma[r]*alpha ----------------
__global__ __launch_bounds__(256) void k_gemm64(const float* __restrict__ A,
                                                const float* __restrict__ B,
                                                const float* __restrict__ gamma,
                                                const float* __restrict__ alpha_p, int ai,
                                                float* __restrict__ C, int cols) {
    __shared__ float As[64][68];  // [k][row]
    __shared__ float Bs[64][68];  // [k][col]
    const int K = DIMM;
    int tid = threadIdx.x;
    int row0 = blockIdx.y * 64;
    int col0 = blockIdx.x * 64;
    int ty = tid >> 4, tx = tid & 15;
    float acc[4][4] = {{0.f}};
    for (int k0 = 0; k0 < K; k0 += 64) {
        #pragma unroll
        for (int i = 0; i < 4; ++i) {
            int li = tid + i * 256;
            int r = li >> 4;   // 0..63
            int c4 = li & 15;  // 0..15
            float4 av = *reinterpret_cast<const float4*>(&A[(size_t)(row0 + r) * K + k0 + c4 * 4]);
            As[c4 * 4 + 0][r] = av.x; As[c4 * 4 + 1][r] = av.y;
            As[c4 * 4 + 2][r] = av.z; As[c4 * 4 + 3][r] = av.w;
            float4 bv = *reinterpret_cast<const float4*>(&B[(size_t)(col0 + r) * K + k0 + c4 * 4]);
            Bs[c4 * 4 + 0][r] = bv.x; Bs[c4 * 4 + 1][r] = bv.y;
            Bs[c4 * 4 + 2][r] = bv.z; Bs[c4 * 4 + 3][r] = bv.w;
        }
        __syncthreads();
        #pragma unroll 8
        for (int k = 0; k < 64; ++k) {
            float4 a4 = *reinterpret_cast<const float4*>(&As[k][ty * 4]);
            float4 b4 = *reinterpret_cast<const float4*>(&Bs[k][tx * 4]);
            float a[4] = {a4.x, a4.y, a4.z, a4.w};
            float b[4] = {b4.x, b4.y, b4.z, b4.w};
            #pragma unroll
            for (int i = 0; i < 4; ++i)
                #pragma unroll
                for (int j = 0; j < 4; ++j) acc[i][j] += a[i] * b[j];
        }
        __syncthreads();
    }
    float alpha = alpha_p[ai];
    #pragma unroll
    for (int i = 0; i < 4; ++i) {
        int r = row0 + ty * 4 + i;
        float sc = gamma[r] * alpha;
        float4 o;
        o.x = acc[i][0] * sc; o.y = acc[i][1] * sc;
        o.z = acc[i][2] * sc; o.w = acc[i][3] * sc;
        *reinterpret_cast<float4*>(&C[(size_t)r * cols + col0 + tx * 4]) = o;
    }
}

// ---------------- rope table ----------------
__global__ __launch_bounds__(256) void k_rope(float* __restrict__ c, float* __restrict__ s) {
    int idx = blockIdx.x * 256 + threadIdx.x;  // < 32768
    int t = idx >> 5, i = idx & 31;
    float inv = 1.0f / powf(10000.0f, (float)(2 * i) * (1.0f / 64.0f));
    float f = (float)t * inv;
    c[idx] = cosf(f);
    s[idx] = sinf(f);
}

// ---------------- q prep: rms_norm + rope + gain -> bf16 [b,h,s,d] ----------------
__global__ __launch_bounds__(256) void k_prep_q(const float* __restrict__ C,
                                                const float* __restrict__ rc,
                                                const float* __restrict__ rs,
                                                const float* __restrict__ gain,
                                                u16* __restrict__ Qo) {
    int lane = threadIdx.x & 63;
    int task = blockIdx.x * 4 + (threadIdx.x >> 6);  // (b*16+h)*1024+s
    int s = task & 1023;
    int h = (task >> 10) & 15;
    int b = task >> 14;
    float xv = C[(((size_t)b * 1024 + s) * 16 + h) * 64 + lane];
    float ss = xv * xv;
    #pragma unroll
    for (int off = 32; off; off >>= 1) ss += __shfl_xor(ss, off);
    float r = 1.0f / sqrtf(ss * (1.0f / 64.0f) + 1.1920929e-07f);
    xv *= r;
    float xp = __shfl_xor(xv, 32);
    int i = lane & 31;
    float c = rc[s * 32 + i], sn = rs[s * 32 + i];
    float y = (lane < 32) ? (xv * c + xp * sn) : (xv * c - xp * sn);
    y *= gain[h];
    Qo[(size_t)task * 64 + lane] = f2bf(y);
}

// ---------------- k prep: rms_norm + rope -> bf16 [b,kv,s,d] ----------------
__global__ __launch_bounds__(256) void k_prep_k(const float* __restrict__ C,
                                                const float* __restrict__ rc,
                                                const float* __restrict__ rs,
                                                u16* __restrict__ Ko) {
    int lane = threadIdx.x & 63;
    int task = blockIdx.x * 4 + (threadIdx.x >> 6);  // (b*4+kv)*1024+s
    int s = task & 1023;
    int kv = (task >> 10) & 3;
    int b = task >> 12;
    float xv = C[(((size_t)b * 1024 + s) * 4 + kv) * 64 + lane];
    float ss = xv * xv;
    #pragma unroll
    for (int off = 32; off; off >>= 1) ss += __shfl_xor(ss, off);
    float r = 1.0f / sqrtf(ss * (1.0f / 64.0f) + 1.1920929e-07f);
    xv *= r;
    float xp = __shfl_xor(xv, 32);
    int i = lane & 31;
    float c = rc[s * 32 + i], sn = rs[s * 32 + i];
    float y = (lane < 32) ? (xv * c + xp * sn) : (xv * c - xp * sn);
    Ko[(size_t)task * 64 + lane] = f2bf(y);
}

// ---------------- v transpose: cv [b,s,kv*64+d] f32 -> Vt [b,kv,d,s] bf16 ----------------
__global__ __launch_bounds__(256) void k_vtransT(const float* __restrict__ Cv,
                                                 u16* __restrict__ Vt) {
    __shared__ u16 T[64][72];
    int st = blockIdx.x, kv = blockIdx.y, b = blockIdx.z;
    int tid = threadIdx.x;
    int sr = tid >> 4, d4 = tid & 15;
    #pragma unroll
    for (int i = 0; i < 4; ++i) {
        int s = sr + 16 * i;
        float4 v = *reinterpret_cast<const float4*>(
            &Cv[(size_t)(b * 1024 + st * 64 + s) * 256 + kv * 64 + d4 * 4]);
        T[d4 * 4 + 0][s] = f2bf(v.x);
        T[d4 * 4 + 1][s] = f2bf(v.y);
        T[d4 * 4 + 2][s] = f2bf(v.z);
        T[d4 * 4 + 3][s] = f2bf(v.w);
    }
    __syncthreads();
    int d = tid >> 2, c = tid & 3;
    float4 o0 = *reinterpret_cast<const float4*>(&T[d][c * 16]);
    float4 o1 = *reinterpret_cast<const float4*>(&T[d][c * 16 + 8]);
    u16* out = &Vt[(((size_t)(b * 4 + kv) * 64) + d) * 1024 + st * 64 + c * 16];
    *reinterpret_cast<float4*>(out) = o0;
    *reinterpret_cast<float4*>(out + 8) = o1;
}

// ---------------- causal flash attention, bf16 MFMA ----------------
// grid (S/64, H, B); 4 waves; wave w owns q-rows [qt*64+16w, +16)
__global__ __launch_bounds__(256) void k_attn_mfma(const u16* __restrict__ Q,
                                                   const u16* __restrict__ K,
                                                   const u16* __restrict__ Vt,
                                                   float* __restrict__ Y) {
    __shared__ u16 Ks[64][72];      // [key][d]
    __shared__ u16 Vs[64][72];      // [d][key]
    __shared__ u16 Ps[4][16][72];   // per-wave P strip [q][key]
    int qt = blockIdx.x, h = blockIdx.y, b = blockIdx.z;
    int kvh = h >> 2;
    int tid = threadIdx.x;
    int w = tid >> 6, lane = tid & 63;
    int lr = lane & 15, lg = lane >> 4;
    int q0 = qt * 64 + w * 16;
    const u16* Qb = Q + (((size_t)b * 16 + h) * 1024) * 64;
    const u16* Kb = K + (((size_t)b * 4 + kvh) * 1024) * 64;
    const u16* Vb = Vt + (((size_t)b * 4 + kvh) * 64) * 1024;

    bf16x8 qf0 = *reinterpret_cast<const bf16x8*>(&Qb[(size_t)(q0 + lr) * 64 + 8 * lg]);
    bf16x8 qf1 = *reinterpret_cast<const bf16x8*>(&Qb[(size_t)(q0 + lr) * 64 + 32 + 8 * lg]);

    float m[4], lden[4];
    f32x4 accY[4];
    #pragma unroll
    for (int r = 0; r < 4; ++r) { m[r] = -INFINITY; lden[r] = 0.f; }
    #pragma unroll
    for (int dt = 0; dt < 4; ++dt) accY[dt] = (f32x4){0.f, 0.f, 0.f, 0.f};

    const float SC = 0.125f * 1.4426950408889634f;  // scale * log2(e)

    for (int t = 0; t <= qt; ++t) {
        const int k0 = t * 64;
        {   // stage K tile [64key][64d], V^T tile [64d][64key]
            int r = tid >> 2, c = tid & 3;
            const float4* gk = reinterpret_cast<const float4*>(&Kb[(size_t)(k0 + r) * 64 + c * 16]);
            float4 ka = gk[0], kb2 = gk[1];
            *reinterpret_cast<float4*>(&Ks[r][c * 16]) = ka;
            *reinterpret_cast<float4*>(&Ks[r][c * 16 + 8]) = kb2;
            const float4* gv = reinterpret_cast<const float4*>(&Vb[(size_t)r * 1024 + k0 + c * 16]);
            float4 va = gv[0], vb = gv[1];
            *reinterpret_cast<float4*>(&Vs[r][c * 16]) = va;
            *reinterpret_cast<float4*>(&Vs[r][c * 16 + 8]) = vb;
        }
        __syncthreads();

        // S = Q K^T : 4 key-tiles of 16
        float sv[4][4];
        #pragma unroll
        for (int t4 = 0; t4 < 4; ++t4) {
            bf16x8 kf0 = *reinterpret_cast<const bf16x8*>(&Ks[t4 * 16 + lr][8 * lg]);
            bf16x8 kf1 = *reinterpret_cast<const bf16x8*>(&Ks[t4 * 16 + lr][32 + 8 * lg]);
            f32x4 z = (f32x4){0.f, 0.f, 0.f, 0.f};
            z = __builtin_amdgcn_mfma_f32_16x16x32_bf16(qf0, kf0, z, 0, 0, 0);
            z = __builtin_amdgcn_mfma_f32_16x16x32_bf16(qf1, kf1, z, 0, 0, 0);
            #pragma unroll
            for (int r = 0; r < 4; ++r) sv[t4][r] = z[r] * SC;
        }
        if (t == qt) {  // causal mask on diagonal tile
            #pragma unroll
            for (int t4 = 0; t4 < 4; ++t4) {
                int key = k0 + t4 * 16 + lr;
                #pragma unroll
                for (int r = 0; r < 4; ++r) {
                    int qg = q0 + lg * 4 + r;
                    if (key > qg) sv[t4][r] = -3.0e38f;
                }
            }
        }

        // online softmax (exp2 domain); rows distributed as (lg*4+r), keys as (t4,lr)
        float p[4][4];
        #pragma unroll
        for (int r = 0; r < 4; ++r) {
            float mm = fmaxf(fmaxf(sv[0][r], sv[1][r]), fmaxf(sv[2][r], sv[3][r]));
            #pragma unroll
            for (int off = 8; off; off >>= 1) mm = fmaxf(mm, __shfl_xor(mm, off));
            float mn = fmaxf(m[r], mm);
            float corr = exp2f(m[r] - mn);
            m[r] = mn;
            float rs = 0.f;
            #pragma unroll
            for (int t4 = 0; t4 < 4; ++t4) { p[t4][r] = exp2f(sv[t4][r] - mn); rs += p[t4][r]; }
            #pragma unroll
            for (int off = 8; off; off >>= 1) rs += __shfl_xor(rs, off);
            lden[r] = lden[r] * corr + rs;
            #pragma unroll
            for (int dt = 0; dt < 4; ++dt) accY[dt][r] *= corr;
        }

        // P -> per-wave LDS strip (re-fragment for PV)
        #pragma unroll
        for (int t4 = 0; t4 < 4; ++t4)
            #pragma unroll
            for (int r = 0; r < 4; ++r)
                Ps[w][lg * 4 + r][t4 * 16 + lr] = f2bf(p[t4][r]);

        bf16x8 pa0 = *reinterpret_cast<const bf16x8*>(&Ps[w][lr][8 * lg]);
        bf16x8 pa1 = *reinterpret_cast<const bf16x8*>(&Ps[w][lr][32 + 8 * lg]);
        #pragma unroll
        for (int dt = 0; dt < 4; ++dt) {
            bf16x8 vf0 = *reinterpret_cast<const bf16x8*>(&Vs[dt * 16 + lr][8 * lg]);
            bf16x8 vf1 = *reinterpret_cast<const bf16x8*>(&Vs[dt * 16 + lr][32 + 8 * lg]);
            accY[dt] = __builtin_amdgcn_mfma_f32_16x16x32_bf16(pa0, vf0, accY[dt], 0, 0, 0);
            accY[dt] = __builtin_amdgcn_mfma_f32_16x16x32_bf16(pa1, vf1, accY[dt], 0, 0, 0);
        }
        __syncthreads();
    }

    #pragma unroll
    for (int r = 0; r < 4; ++r) {
        float inv = 1.0f / lden[r];
        size_t base = ((size_t)(b * 1024 + q0 + lg * 4 + r)) * 1024 + h * 64;
        #pragma unroll
        for (int dt = 0; dt < 4; ++dt)
            Y[base + dt * 16 + lr] = accY[dt][r] * inv;
    }
}

extern "C" void kernel_launch(void* const* d_in, const int* in_sizes, int n_in,
                              void* d_out, int out_size, void* d_ws, size_t ws_size,
                              hipStream_t stream) {
    (void)in_sizes; (void)n_in; (void)out_size; (void)ws_size;
    const float* x  = (const float*)d_in[0];
    const float* Wq = (const float*)d_in[1];
    const float* Wk = (const float*)d_in[2];
    const float* Wv = (const float*)d_in[3];
    const float* Wp = (const float*)d_in[4];
    const float* qg = (const float*)d_in[5];
    float* out = (float*)d_out;

    float* p = (float*)d_ws;
    float* partial = p; p += 256;
    float* alpha = p;   p += 16;
    float* wtq = p; p += 1048576;
    float* wtk = p; p += 262144;
    float* wtv = p; p += 262144;
    float* wtp = p; p += 1048576;
    float* xq  = p; p += 8388608;
    float* gam = p; p += 8192;
    float* cq  = p; p += 8388608;
    float* ck  = p; p += 2097152;
    float* cv  = p; p += 2097152;
    u16*   qo  = (u16*)p; p += 8388608;  // bf16 [b,h,s,64]
    u16*   ko  = (u16*)p; p += 2097152;  // bf16 [b,kv,s,64]
    u16*   vt  = (u16*)p; p += 2097152;  // bf16 [b,kv,64,s]
    float* rc  = p; p += 32768;
    float* rs  = p; p += 32768;
    float* y   = cq;   // reuse (cq dead after prep_q)
    float* yq  = xq;   // reuse (xq dead after qkv gemms)

    // weight quantization
    k_absmean<<<64, 256, 0, stream>>>(Wq, 1048576, partial + 0);
    k_absmean<<<64, 256, 0, stream>>>(Wk, 262144, partial + 64);
    k_absmean<<<64, 256, 0, stream>>>(Wv, 262144, partial + 128);
    k_absmean<<<64, 256, 0, stream>>>(Wp, 1048576, partial + 192);
    k_alpha<<<1, 64, 0, stream>>>(partial, alpha);
    k_tern<<<1024, 256, 0, stream>>>(Wq, alpha, 0, wtq, 1048576);
    k_tern<<<256, 256, 0, stream>>>(Wk, alpha, 1, wtk, 262144);
    k_tern<<<256, 256, 0, stream>>>(Wv, alpha, 2, wtv, 262144);
    k_tern<<<1024, 256, 0, stream>>>(Wp, alpha, 3, wtp, 1048576);

    // rope table
    k_rope<<<128, 256, 0, stream>>>(rc, rs);

    // activation quantization + projections
    k_quant<<<ROWS, 256, 0, stream>>>(x, xq, gam);
    k_gemm64<<<dim3(16, 128), 256, 0, stream>>>(xq, wtq, gam, alpha, 0, cq, 1024);
    k_gemm64<<<dim3(4, 128), 256, 0, stream>>>(xq, wtk, gam, alpha, 1, ck, 256);
    k_gemm64<<<dim3(4, 128), 256, 0, stream>>>(xq, wtv, gam, alpha, 2, cv, 256);

    // norm + rope + layout (bf16 outputs for MFMA attention)
    k_prep_q<<<32768, 256, 0, stream>>>(cq, rc, rs, qg, qo);
    k_prep_k<<<8192, 256, 0, stream>>>(ck, rc, rs, ko);
    k_vtransT<<<dim3(16, 4, 8), 256, 0, stream>>>(cv, vt);

    // attention (bf16 MFMA flash)
    k_attn_mfma<<<dim3(16, 16, 8), 256, 0, stream>>>(qo, ko, vt, y);

    // output projection
    k_quant<<<ROWS, 256, 0, stream>>>(y, yq, gam);
    k_gemm64<<<dim3(16, 128), 256, 0, stream>>>(yq, wtp, gam, alpha, 3, out, 1024);
}

// Round 3
// 320.313 us; speedup vs baseline: 5.7993x; 2.8679x over previous
//
#include <hip/hip_runtime.h>
#include <cmath>

#define DIMM 1024
#define NHEADS 16
#define NKV 4
#define HD 64
#define SEQ 1024
#define BSZ 8
#define ROWS (BSZ * SEQ)   // 8192

typedef unsigned short u16;
typedef __attribute__((ext_vector_type(8))) short bf16x8;
typedef __attribute__((ext_vector_type(4))) float f32x4;
typedef __attribute__((ext_vector_type(4))) unsigned short u16x4;

static __device__ __forceinline__ u16 f2bf(float f) {
    union { float f; unsigned u; } v; v.f = f;
    unsigned r = v.u + 0x7FFFu + ((v.u >> 16) & 1u);
    return (u16)(r >> 16);
}

// async global->LDS, 16B per lane; dst must be wave-uniform base (HW adds lane*16)
static __device__ __forceinline__ void gload16(const u16* g, u16* l) {
    __builtin_amdgcn_global_load_lds(
        (const __attribute__((address_space(1))) unsigned int*)g,
        (__attribute__((address_space(3))) unsigned int*)l, 16, 0, 0);
}

// ---------------- weight abs-mean partial reduce ----------------
__global__ __launch_bounds__(256) void k_absmean(const float* __restrict__ w, int n,
                                                 float* __restrict__ partial) {
    float s = 0.f;
    for (int i = blockIdx.x * 256 + threadIdx.x; i < n; i += 64 * 256) s += fabsf(w[i]);
    #pragma unroll
    for (int off = 32; off; off >>= 1) s += __shfl_xor(s, off);
    __shared__ float red[4];
    if ((threadIdx.x & 63) == 0) red[threadIdx.x >> 6] = s;
    __syncthreads();
    if (threadIdx.x == 0) partial[blockIdx.x] = red[0] + red[1] + red[2] + red[3];
}

// ---------------- alpha = max(mean|w|, eps) ----------------
__global__ void k_alpha(const float* __restrict__ partial, float* __restrict__ alpha) {
    int i = threadIdx.x;
    if (i < 4) {
        const int ns[4] = {1048576, 262144, 262144, 1048576};
        float s = 0.f;
        for (int j = 0; j < 64; ++j) s += partial[i * 64 + j];
        alpha[i] = fmaxf(s / (float)ns[i], 1e-8f);
    }
}

// ---------------- ternarize -> bf16 (values {-1,0,1}, exact) ----------------
__global__ __launch_bounds__(256) void k_tern(const float* __restrict__ w,
                                              const float* __restrict__ alpha, int ai,
                                              u16* __restrict__ wt, int n4) {
    float a = alpha[ai];
    for (int i = blockIdx.x * blockDim.x + threadIdx.x; i < n4; i += gridDim.x * blockDim.x) {
        float4 v = *reinterpret_cast<const float4*>(&w[i * 4]);
        u16x4 o;
        o.x = f2bf(rintf(fminf(fmaxf(v.x / a, -1.f), 1.f)));
        o.y = f2bf(rintf(fminf(fmaxf(v.y / a, -1.f), 1.f)));
        o.z = f2bf(rintf(fminf(fmaxf(v.z / a, -1.f), 1.f)));
        o.w = f2bf(rintf(fminf(fmaxf(v.w / a, -1.f), 1.f)));
        *reinterpret_cast<u16x4*>(&wt[i * 4]) = o;
    }
}

// ---------------- per-row activation quantization -> bf16 ints ----------------
__global__ __launch_bounds__(256) void k_quant(const float* __restrict__ X,
                                               u16* __restrict__ Xq, float* __restrict__ g) {
    int row = blockIdx.x;
    const float* xr = X + (size_t)row * DIMM;
    float4 v = *reinterpret_cast<const float4*>(&xr[threadIdx.x * 4]);
    float mv = fmaxf(fmaxf(fabsf(v.x), fabsf(v.y)), fmaxf(fabsf(v.z), fabsf(v.w)));
    #pragma unroll
    for (int off = 32; off; off >>= 1) mv = fmaxf(mv, __shfl_xor(mv, off));
    __shared__ float red[4];
    if ((threadIdx.x & 63) == 0) red[threadIdx.x >> 6] = mv;
    __syncthreads();
    mv = fmaxf(fmaxf(red[0], red[1]), fmaxf(red[2], red[3]));
    float gamma = fmaxf(mv, 1e-8f) / 127.0f;
    u16x4 o;
    o.x = f2bf(rintf(fminf(fmaxf(v.x / gamma, -128.f), 127.f)));
    o.y = f2bf(rintf(fminf(fmaxf(v.y / gamma, -128.f), 127.f)));
    o.z = f2bf(rintf(fminf(fmaxf(v.z / gamma, -128.f), 127.f)));
    o.w = f2bf(rintf(fminf(fmaxf(v.w / gamma, -128.f), 127.f)));
    *reinterpret_cast<u16x4*>(&Xq[(size_t)row * DIMM + threadIdx.x * 4]) = o;
    if (threadIdx.x == 0) g[row] = gamma;
}

// ---------------- bf16 MFMA GEMM: C[r][c] = (A[r,:]·B[c,:]) * gamma[r] * alpha ----------------
// A: ROWS x 1024 bf16-int, B: cols x 1024 bf16-ternary. 128x128 tile, BK=64,
// 4 waves (2x2), each 64x64 = 4x4 fragments of 16x16x32. global_load_lds staging.
// ai2 >= 0: columns >= 256 use alpha[ai2] (fused KV gemm).
__global__ __launch_bounds__(256) void k_gemm_mfma(const u16* __restrict__ A,
                                                   const u16* __restrict__ B,
                                                   const float* __restrict__ gamma,
                                                   const float* __restrict__ alpha_p, int ai, int ai2,
                                                   float* __restrict__ C, int cols) {
    __shared__ u16 As[128 * 64];
    __shared__ u16 Bs[128 * 64];
    const int K = DIMM;
    int tid = threadIdx.x;
    int w = tid >> 6, lane = tid & 63;
    int lr = lane & 15, lg = lane >> 4;
    int wm = w >> 1, wn = w & 1;
    int row0 = blockIdx.y * 128, col0 = blockIdx.x * 128;

    f32x4 acc[4][4];
    #pragma unroll
    for (int mf = 0; mf < 4; ++mf)
        #pragma unroll
        for (int nf = 0; nf < 4; ++nf) acc[mf][nf] = (f32x4){0.f, 0.f, 0.f, 0.f};

    // staging geometry: chunk c = w*4+i covers rows c*8..c*8+7 of the 128-row tile
    int srow = w * 32 + (lane >> 3);      // + i*8
    int scol = (lane & 7) * 8;
    const u16* Ag = A + (size_t)(row0 + srow) * K + scol;
    const u16* Bg = B + (size_t)(col0 + srow) * K + scol;

    for (int k0 = 0; k0 < K; k0 += 64) {
        #pragma unroll
        for (int i = 0; i < 4; ++i) {
            gload16(Ag + (size_t)i * 8 * K + k0, &As[w * 2048 + i * 512]);
            gload16(Bg + (size_t)i * 8 * K + k0, &Bs[w * 2048 + i * 512]);
        }
        __syncthreads();
        #pragma unroll
        for (int kk = 0; kk < 64; kk += 32) {
            bf16x8 af[4], bfr[4];
            #pragma unroll
            for (int mf = 0; mf < 4; ++mf)
                af[mf] = *reinterpret_cast<const bf16x8*>(&As[(wm * 64 + mf * 16 + lr) * 64 + kk + 8 * lg]);
            #pragma unroll
            for (int nf = 0; nf < 4; ++nf)
                bfr[nf] = *reinterpret_cast<const bf16x8*>(&Bs[(wn * 64 + nf * 16 + lr) * 64 + kk + 8 * lg]);
            #pragma unroll
            for (int mf = 0; mf < 4; ++mf)
                #pragma unroll
                for (int nf = 0; nf < 4; ++nf)
                    acc[mf][nf] = __builtin_amdgcn_mfma_f32_16x16x32_bf16(af[mf], bfr[nf], acc[mf][nf], 0, 0, 0);
        }
        __syncthreads();
    }

    int a_idx = (ai2 >= 0 && col0 >= 256) ? ai2 : ai;
    float alpha = alpha_p[a_idx];
    #pragma unroll
    for (int mf = 0; mf < 4; ++mf) {
        #pragma unroll
        for (int reg = 0; reg < 4; ++reg) {
            int row = row0 + wm * 64 + mf * 16 + lg * 4 + reg;
            float sc = gamma[row] * alpha;
            #pragma unroll
            for (int nf = 0; nf < 4; ++nf)
                C[(size_t)row * cols + col0 + wn * 64 + nf * 16 + lr] = acc[mf][nf][reg] * sc;
        }
    }
}

// ---------------- rope table ----------------
__global__ __launch_bounds__(256) void k_rope(float* __restrict__ c, float* __restrict__ s) {
    int idx = blockIdx.x * 256 + threadIdx.x;  // < 32768
    int t = idx >> 5, i = idx & 31;
    float inv = 1.0f / powf(10000.0f, (float)(2 * i) * (1.0f / 64.0f));
    float f = (float)t * inv;
    c[idx] = cosf(f);
    s[idx] = sinf(f);
}

// ---------------- q prep: rms_norm + rope + gain -> bf16 [b,h,s,d] ----------------
__global__ __launch_bounds__(256) void k_prep_q(const float* __restrict__ C,
                                                const float* __restrict__ rc,
                                                const float* __restrict__ rs,
                                                const float* __restrict__ gain,
                                                u16* __restrict__ Qo) {
    int lane = threadIdx.x & 63;
    int task = blockIdx.x * 4 + (threadIdx.x >> 6);  // (b*16+h)*1024+s
    int s = task & 1023;
    int h = (task >> 10) & 15;
    int b = task >> 14;
    float xv = C[(((size_t)b * 1024 + s) * 16 + h) * 64 + lane];
    float ss = xv * xv;
    #pragma unroll
    for (int off = 32; off; off >>= 1) ss += __shfl_xor(ss, off);
    float r = 1.0f / sqrtf(ss * (1.0f / 64.0f) + 1.1920929e-07f);
    xv *= r;
    float xp = __shfl_xor(xv, 32);
    int i = lane & 31;
    float c = rc[s * 32 + i], sn = rs[s * 32 + i];
    float y = (lane < 32) ? (xv * c + xp * sn) : (xv * c - xp * sn);
    y *= gain[h];
    Qo[(size_t)task * 64 + lane] = f2bf(y);
}

// ---------------- k prep (reads fused KV gemm output, cols=512) ----------------
__global__ __launch_bounds__(256) void k_prep_k(const float* __restrict__ Ckv,
                                                const float* __restrict__ rc,
                                                const float* __restrict__ rs,
                                                u16* __restrict__ Ko) {
    int lane = threadIdx.x & 63;
    int task = blockIdx.x * 4 + (threadIdx.x >> 6);  // (b*4+kv)*1024+s
    int s = task & 1023;
    int kv = (task >> 10) & 3;
    int b = task >> 12;
    float xv = Ckv[((size_t)b * 1024 + s) * 512 + kv * 64 + lane];
    float ss = xv * xv;
    #pragma unroll
    for (int off = 32; off; off >>= 1) ss += __shfl_xor(ss, off);
    float r = 1.0f / sqrtf(ss * (1.0f / 64.0f) + 1.1920929e-07f);
    xv *= r;
    float xp = __shfl_xor(xv, 32);
    int i = lane & 31;
    float c = rc[s * 32 + i], sn = rs[s * 32 + i];
    float y = (lane < 32) ? (xv * c + xp * sn) : (xv * c - xp * sn);
    Ko[(size_t)task * 64 + lane] = f2bf(y);
}

// ---------------- v transpose: Ckv [b,s,512] (+256 offset) -> Vt [b,kv,d,s] bf16 ----------------
__global__ __launch_bounds__(256) void k_vtransT(const float* __restrict__ Ckv,
                                                 u16* __restrict__ Vt) {
    __shared__ u16 T[64][72];
    int st = blockIdx.x, kv = blockIdx.y, b = blockIdx.z;
    int tid = threadIdx.x;
    int sr = tid >> 4, d4 = tid & 15;
    #pragma unroll
    for (int i = 0; i < 4; ++i) {
        int s = sr + 16 * i;
        float4 v = *reinterpret_cast<const float4*>(
            &Ckv[(size_t)(b * 1024 + st * 64 + s) * 512 + 256 + kv * 64 + d4 * 4]);
        T[d4 * 4 + 0][s] = f2bf(v.x);
        T[d4 * 4 + 1][s] = f2bf(v.y);
        T[d4 * 4 + 2][s] = f2bf(v.z);
        T[d4 * 4 + 3][s] = f2bf(v.w);
    }
    __syncthreads();
    int d = tid >> 2, c = tid & 3;
    float4 o0 = *reinterpret_cast<const float4*>(&T[d][c * 16]);
    float4 o1 = *reinterpret_cast<const float4*>(&T[d][c * 16 + 8]);
    u16* out = &Vt[(((size_t)(b * 4 + kv) * 64) + d) * 1024 + st * 64 + c * 16];
    *reinterpret_cast<float4*>(out) = o0;
    *reinterpret_cast<float4*>(out + 8) = o1;
}

// ---------------- causal flash attention, bf16 MFMA ----------------
__global__ __launch_bounds__(256) void k_attn_mfma(const u16* __restrict__ Q,
                                                   const u16* __restrict__ K,
                                                   const u16* __restrict__ Vt,
                                                   float* __restrict__ Y) {
    __shared__ u16 Ks[64][72];      // [key][d]
    __shared__ u16 Vs[64][72];      // [d][key]
    __shared__ u16 Ps[4][16][72];   // per-wave P strip [q][key]
    int qt = blockIdx.x, h = blockIdx.y, b = blockIdx.z;
    int kvh = h >> 2;
    int tid = threadIdx.x;
    int w = tid >> 6, lane = tid & 63;
    int lr = lane & 15, lg = lane >> 4;
    int q0 = qt * 64 + w * 16;
    const u16* Qb = Q + (((size_t)b * 16 + h) * 1024) * 64;
    const u16* Kb = K + (((size_t)b * 4 + kvh) * 1024) * 64;
    const u16* Vb = Vt + (((size_t)b * 4 + kvh) * 64) * 1024;

    bf16x8 qf0 = *reinterpret_cast<const bf16x8*>(&Qb[(size_t)(q0 + lr) * 64 + 8 * lg]);
    bf16x8 qf1 = *reinterpret_cast<const bf16x8*>(&Qb[(size_t)(q0 + lr) * 64 + 32 + 8 * lg]);

    float m[4], lden[4];
    f32x4 accY[4];
    #pragma unroll
    for (int r = 0; r < 4; ++r) { m[r] = -INFINITY; lden[r] = 0.f; }
    #pragma unroll
    for (int dt = 0; dt < 4; ++dt) accY[dt] = (f32x4){0.f, 0.f, 0.f, 0.f};

    const float SC = 0.125f * 1.4426950408889634f;  // scale * log2(e)

    for (int t = 0; t <= qt; ++t) {
        const int k0 = t * 64;
        {   // stage K tile [64key][64d], V^T tile [64d][64key]
            int r = tid >> 2, c = tid & 3;
            const float4* gk = reinterpret_cast<const float4*>(&Kb[(size_t)(k0 + r) * 64 + c * 16]);
            float4 ka = gk[0], kb2 = gk[1];
            *reinterpret_cast<float4*>(&Ks[r][c * 16]) = ka;
            *reinterpret_cast<float4*>(&Ks[r][c * 16 + 8]) = kb2;
            const float4* gv = reinterpret_cast<const float4*>(&Vb[(size_t)r * 1024 + k0 + c * 16]);
            float4 va = gv[0], vb = gv[1];
            *reinterpret_cast<float4*>(&Vs[r][c * 16]) = va;
            *reinterpret_cast<float4*>(&Vs[r][c * 16 + 8]) = vb;
        }
        __syncthreads();

        float sv[4][4];
        #pragma unroll
        for (int t4 = 0; t4 < 4; ++t4) {
            bf16x8 kf0 = *reinterpret_cast<const bf16x8*>(&Ks[t4 * 16 + lr][8 * lg]);
            bf16x8 kf1 = *reinterpret_cast<const bf16x8*>(&Ks[t4 * 16 + lr][32 + 8 * lg]);
            f32x4 z = (f32x4){0.f, 0.f, 0.f, 0.f};
            z = __builtin_amdgcn_mfma_f32_16x16x32_bf16(qf0, kf0, z, 0, 0, 0);
            z = __builtin_amdgcn_mfma_f32_16x16x32_bf16(qf1, kf1, z, 0, 0, 0);
            #pragma unroll
            for (int r = 0; r < 4; ++r) sv[t4][r] = z[r] * SC;
        }
        if (t == qt) {
            #pragma unroll
            for (int t4 = 0; t4 < 4; ++t4) {
                int key = k0 + t4 * 16 + lr;
                #pragma unroll
                for (int r = 0; r < 4; ++r) {
                    int qg = q0 + lg * 4 + r;
                    if (key > qg) sv[t4][r] = -3.0e38f;
                }
            }
        }

        float p[4][4];
        #pragma unroll
        for (int r = 0; r < 4; ++r) {
            float mm = fmaxf(fmaxf(sv[0][r], sv[1][r]), fmaxf(sv[2][r], sv[3][r]));
            #pragma unroll
            for (int off = 8; off; off >>= 1) mm = fmaxf(mm, __shfl_xor(mm, off));
            float mn = fmaxf(m[r], mm);
            float corr = exp2f(m[r] - mn);
            m[r] = mn;
            float rs = 0.f;
            #pragma unroll
            for (int t4 = 0; t4 < 4; ++t4) { p[t4][r] = exp2f(sv[t4][r] - mn); rs += p[t4][r]; }
            #pragma unroll
            for (int off = 8; off; off >>= 1) rs += __shfl_xor(rs, off);
            lden[r] = lden[r] * corr + rs;
            #pragma unroll
            for (int dt = 0; dt < 4; ++dt) accY[dt][r] *= corr;
        }

        #pragma unroll
        for (int t4 = 0; t4 < 4; ++t4)
            #pragma unroll
            for (int r = 0; r < 4; ++r)
                Ps[w][lg * 4 + r][t4 * 16 + lr] = f2bf(p[t4][r]);

        bf16x8 pa0 = *reinterpret_cast<const bf16x8*>(&Ps[w][lr][8 * lg]);
        bf16x8 pa1 = *reinterpret_cast<const bf16x8*>(&Ps[w][lr][32 + 8 * lg]);
        #pragma unroll
        for (int dt = 0; dt < 4; ++dt) {
            bf16x8 vf0 = *reinterpret_cast<const bf16x8*>(&Vs[dt * 16 + lr][8 * lg]);
            bf16x8 vf1 = *reinterpret_cast<const bf16x8*>(&Vs[dt * 16 + lr][32 + 8 * lg]);
            accY[dt] = __builtin_amdgcn_mfma_f32_16x16x32_bf16(pa0, vf0, accY[dt], 0, 0, 0);
            accY[dt] = __builtin_amdgcn_mfma_f32_16x16x32_bf16(pa1, vf1, accY[dt], 0, 0, 0);
        }
        __syncthreads();
    }

    #pragma unroll
    for (int r = 0; r < 4; ++r) {
        float inv = 1.0f / lden[r];
        size_t base = ((size_t)(b * 1024 + q0 + lg * 4 + r)) * 1024 + h * 64;
        #pragma unroll
        for (int dt = 0; dt < 4; ++dt)
            Y[base + dt * 16 + lr] = accY[dt][r] * inv;
    }
}

extern "C" void kernel_launch(void* const* d_in, const int* in_sizes, int n_in,
                              void* d_out, int out_size, void* d_ws, size_t ws_size,
                              hipStream_t stream) {
    (void)in_sizes; (void)n_in; (void)out_size; (void)ws_size;
    const float* x  = (const float*)d_in[0];
    const float* Wq = (const float*)d_in[1];
    const float* Wk = (const float*)d_in[2];
    const float* Wv = (const float*)d_in[3];
    const float* Wp = (const float*)d_in[4];
    const float* qg = (const float*)d_in[5];
    float* out = (float*)d_out;

    float* p = (float*)d_ws;
    float* partial = p; p += 256;
    float* alpha = p;   p += 16;
    u16* wtq  = (u16*)p; p += 524288;   // 1M u16
    u16* wtkv = (u16*)p; p += 262144;   // 512K u16 (Wk rows 0..255, Wv rows 256..511)
    u16* wtp  = (u16*)p; p += 524288;   // 1M u16
    u16* xq   = (u16*)p; p += 4194304;  // 8M u16
    float* gam = p; p += 8192;
    float* cq  = p; p += 8388608;       // f32 [8192][1024]
    float* ckv = p; p += 4194304;       // f32 [8192][512]
    u16* qo = (u16*)p; p += 4194304;    // bf16 [b,h,s,64]
    u16* ko = (u16*)p; p += 1048576;    // bf16 [b,kv,s,64]
    u16* vt = (u16*)p; p += 1048576;    // bf16 [b,kv,64,s]
    float* rc = p; p += 32768;
    float* rs = p; p += 32768;
    float* y  = cq;        // reuse (cq dead after prep_q)
    u16*   yq = xq;        // reuse (xq dead after qkv gemms)

    // weight quantization
    k_absmean<<<64, 256, 0, stream>>>(Wq, 1048576, partial + 0);
    k_absmean<<<64, 256, 0, stream>>>(Wk, 262144, partial + 64);
    k_absmean<<<64, 256, 0, stream>>>(Wv, 262144, partial + 128);
    k_absmean<<<64, 256, 0, stream>>>(Wp, 1048576, partial + 192);
    k_alpha<<<1, 64, 0, stream>>>(partial, alpha);
    k_tern<<<512, 256, 0, stream>>>(Wq, alpha, 0, wtq, 262144);
    k_tern<<<128, 256, 0, stream>>>(Wk, alpha, 1, wtkv, 65536);
    k_tern<<<128, 256, 0, stream>>>(Wv, alpha, 2, wtkv + 262144, 65536);
    k_tern<<<512, 256, 0, stream>>>(Wp, alpha, 3, wtp, 262144);

    // rope table
    k_rope<<<128, 256, 0, stream>>>(rc, rs);

    // activation quantization + projections (bf16 MFMA, exact integer math)
    k_quant<<<ROWS, 256, 0, stream>>>(x, xq, gam);
    k_gemm_mfma<<<dim3(8, 64), 256, 0, stream>>>(xq, wtq, gam, alpha, 0, -1, cq, 1024);
    k_gemm_mfma<<<dim3(4, 64), 256, 0, stream>>>(xq, wtkv, gam, alpha, 1, 2, ckv, 512);

    // norm + rope + layout
    k_prep_q<<<32768, 256, 0, stream>>>(cq, rc, rs, qg, qo);
    k_prep_k<<<8192, 256, 0, stream>>>(ckv, rc, rs, ko);
    k_vtransT<<<dim3(16, 4, 8), 256, 0, stream>>>(ckv, vt);

    // attention (bf16 MFMA flash)
    k_attn_mfma<<<dim3(16, 16, 8), 256, 0, stream>>>(qo, ko, vt, y);

    // output projection
    k_quant<<<ROWS, 256, 0, stream>>>(y, yq, gam);
    k_gemm_mfma<<<dim3(8, 64), 256, 0, stream>>>(yq, wtp, gam, alpha, 3, -1, out, 1024);
}

// Round 4
// 293.118 us; speedup vs baseline: 6.3374x; 1.0928x over previous
//
#include <hip/hip_runtime.h>
#include <cmath>

#define DIMM 1024
#define NHEADS 16
#define NKV 4
#define HD 64
#define SEQ 1024
#define BSZ 8
#define ROWS (BSZ * SEQ)   // 8192

typedef unsigned short u16;
typedef __attribute__((ext_vector_type(8))) short bf16x8;
typedef __attribute__((ext_vector_type(4))) float f32x4;
typedef __attribute__((ext_vector_type(4))) unsigned short u16x4;

static __device__ __forceinline__ u16 f2bf(float f) {
    union { float f; unsigned u; } v; v.f = f;
    unsigned r = v.u + 0x7FFFu + ((v.u >> 16) & 1u);
    return (u16)(r >> 16);
}

// async global->LDS, 16B per lane; dst must be wave-uniform base (HW adds lane*16)
static __device__ __forceinline__ void gload16(const u16* g, u16* l) {
    __builtin_amdgcn_global_load_lds(
        (const __attribute__((address_space(1))) unsigned int*)g,
        (__attribute__((address_space(3))) unsigned int*)l, 16, 0, 0);
}

// ---------------- weight abs-mean partial reduce ----------------
__global__ __launch_bounds__(256) void k_absmean(const float* __restrict__ w, int n,
                                                 float* __restrict__ partial) {
    float s = 0.f;
    for (int i = blockIdx.x * 256 + threadIdx.x; i < n; i += 64 * 256) s += fabsf(w[i]);
    #pragma unroll
    for (int off = 32; off; off >>= 1) s += __shfl_xor(s, off);
    __shared__ float red[4];
    if ((threadIdx.x & 63) == 0) red[threadIdx.x >> 6] = s;
    __syncthreads();
    if (threadIdx.x == 0) partial[blockIdx.x] = red[0] + red[1] + red[2] + red[3];
}

// ---------------- alpha = max(mean|w|, eps) ----------------
__global__ void k_alpha(const float* __restrict__ partial, float* __restrict__ alpha) {
    int i = threadIdx.x;
    if (i < 4) {
        const int ns[4] = {1048576, 262144, 262144, 1048576};
        float s = 0.f;
        for (int j = 0; j < 64; ++j) s += partial[i * 64 + j];
        alpha[i] = fmaxf(s / (float)ns[i], 1e-8f);
    }
}

// ---------------- ternarize -> bf16 (values {-1,0,1}, exact) ----------------
__global__ __launch_bounds__(256) void k_tern(const float* __restrict__ w,
                                              const float* __restrict__ alpha, int ai,
                                              u16* __restrict__ wt, int n4) {
    float a = alpha[ai];
    for (int i = blockIdx.x * blockDim.x + threadIdx.x; i < n4; i += gridDim.x * blockDim.x) {
        float4 v = *reinterpret_cast<const float4*>(&w[i * 4]);
        u16x4 o;
        o.x = f2bf(rintf(fminf(fmaxf(v.x / a, -1.f), 1.f)));
        o.y = f2bf(rintf(fminf(fmaxf(v.y / a, -1.f), 1.f)));
        o.z = f2bf(rintf(fminf(fmaxf(v.z / a, -1.f), 1.f)));
        o.w = f2bf(rintf(fminf(fmaxf(v.w / a, -1.f), 1.f)));
        *reinterpret_cast<u16x4*>(&wt[i * 4]) = o;
    }
}

// ---------------- per-row activation quantization -> bf16 ints ----------------
__global__ __launch_bounds__(256) void k_quant(const float* __restrict__ X,
                                               u16* __restrict__ Xq, float* __restrict__ g) {
    int row = blockIdx.x;
    const float* xr = X + (size_t)row * DIMM;
    float4 v = *reinterpret_cast<const float4*>(&xr[threadIdx.x * 4]);
    float mv = fmaxf(fmaxf(fabsf(v.x), fabsf(v.y)), fmaxf(fabsf(v.z), fabsf(v.w)));
    #pragma unroll
    for (int off = 32; off; off >>= 1) mv = fmaxf(mv, __shfl_xor(mv, off));
    __shared__ float red[4];
    if ((threadIdx.x & 63) == 0) red[threadIdx.x >> 6] = mv;
    __syncthreads();
    mv = fmaxf(fmaxf(red[0], red[1]), fmaxf(red[2], red[3]));
    float gamma = fmaxf(mv, 1e-8f) / 127.0f;
    u16x4 o;
    o.x = f2bf(rintf(fminf(fmaxf(v.x / gamma, -128.f), 127.f)));
    o.y = f2bf(rintf(fminf(fmaxf(v.y / gamma, -128.f), 127.f)));
    o.z = f2bf(rintf(fminf(fmaxf(v.z / gamma, -128.f), 127.f)));
    o.w = f2bf(rintf(fminf(fmaxf(v.w / gamma, -128.f), 127.f)));
    *reinterpret_cast<u16x4*>(&Xq[(size_t)row * DIMM + threadIdx.x * 4]) = o;
    if (threadIdx.x == 0) g[row] = gamma;
}

// ---------------- bf16 MFMA GEMM (m97 structure) ----------------
__global__ __launch_bounds__(256) void k_gemm_mfma(const u16* __restrict__ A,
                                                   const u16* __restrict__ B,
                                                   const float* __restrict__ gamma,
                                                   const float* __restrict__ alpha_p, int ai, int ai2,
                                                   float* __restrict__ C, int cols) {
    __shared__ u16 As[128 * 64];
    __shared__ u16 Bs[128 * 64];
    const int K = DIMM;
    int tid = threadIdx.x;
    int w = tid >> 6, lane = tid & 63;
    int lr = lane & 15, lg = lane >> 4;
    int wm = w >> 1, wn = w & 1;
    int row0 = blockIdx.y * 128, col0 = blockIdx.x * 128;

    f32x4 acc[4][4];
    #pragma unroll
    for (int mf = 0; mf < 4; ++mf)
        #pragma unroll
        for (int nf = 0; nf < 4; ++nf) acc[mf][nf] = (f32x4){0.f, 0.f, 0.f, 0.f};

    int srow = w * 32 + (lane >> 3);
    int scol = (lane & 7) * 8;
    const u16* Ag = A + (size_t)(row0 + srow) * K + scol;
    const u16* Bg = B + (size_t)(col0 + srow) * K + scol;

    for (int k0 = 0; k0 < K; k0 += 64) {
        #pragma unroll
        for (int i = 0; i < 4; ++i) {
            gload16(Ag + (size_t)i * 8 * K + k0, &As[w * 2048 + i * 512]);
            gload16(Bg + (size_t)i * 8 * K + k0, &Bs[w * 2048 + i * 512]);
        }
        __syncthreads();
        #pragma unroll
        for (int kk = 0; kk < 64; kk += 32) {
            bf16x8 af[4], bfr[4];
            #pragma unroll
            for (int mf = 0; mf < 4; ++mf)
                af[mf] = *reinterpret_cast<const bf16x8*>(&As[(wm * 64 + mf * 16 + lr) * 64 + kk + 8 * lg]);
            #pragma unroll
            for (int nf = 0; nf < 4; ++nf)
                bfr[nf] = *reinterpret_cast<const bf16x8*>(&Bs[(wn * 64 + nf * 16 + lr) * 64 + kk + 8 * lg]);
            #pragma unroll
            for (int mf = 0; mf < 4; ++mf)
                #pragma unroll
                for (int nf = 0; nf < 4; ++nf)
                    acc[mf][nf] = __builtin_amdgcn_mfma_f32_16x16x32_bf16(af[mf], bfr[nf], acc[mf][nf], 0, 0, 0);
        }
        __syncthreads();
    }

    int a_idx = (ai2 >= 0 && col0 >= 256) ? ai2 : ai;
    float alpha = alpha_p[a_idx];
    #pragma unroll
    for (int mf = 0; mf < 4; ++mf) {
        #pragma unroll
        for (int reg = 0; reg < 4; ++reg) {
            int row = row0 + wm * 64 + mf * 16 + lg * 4 + reg;
            float sc = gamma[row] * alpha;
            #pragma unroll
            for (int nf = 0; nf < 4; ++nf)
                C[(size_t)row * cols + col0 + wn * 64 + nf * 16 + lr] = acc[mf][nf][reg] * sc;
        }
    }
}

// ---------------- rope table ----------------
__global__ __launch_bounds__(256) void k_rope(float* __restrict__ c, float* __restrict__ s) {
    int idx = blockIdx.x * 256 + threadIdx.x;  // < 32768
    int t = idx >> 5, i = idx & 31;
    float inv = 1.0f / powf(10000.0f, (float)(2 * i) * (1.0f / 64.0f));
    float f = (float)t * inv;
    c[idx] = cosf(f);
    s[idx] = sinf(f);
}

// ---------------- q prep: rms_norm + rope + gain -> bf16 [b,h,s,d] ----------------
__global__ __launch_bounds__(256) void k_prep_q(const float* __restrict__ C,
                                                const float* __restrict__ rc,
                                                const float* __restrict__ rs,
                                                const float* __restrict__ gain,
                                                u16* __restrict__ Qo) {
    int lane = threadIdx.x & 63;
    int task = blockIdx.x * 4 + (threadIdx.x >> 6);  // (b*16+h)*1024+s
    int s = task & 1023;
    int h = (task >> 10) & 15;
    int b = task >> 14;
    float xv = C[(((size_t)b * 1024 + s) * 16 + h) * 64 + lane];
    float ss = xv * xv;
    #pragma unroll
    for (int off = 32; off; off >>= 1) ss += __shfl_xor(ss, off);
    float r = 1.0f / sqrtf(ss * (1.0f / 64.0f) + 1.1920929e-07f);
    xv *= r;
    float xp = __shfl_xor(xv, 32);
    int i = lane & 31;
    float c = rc[s * 32 + i], sn = rs[s * 32 + i];
    float y = (lane < 32) ? (xv * c + xp * sn) : (xv * c - xp * sn);
    y *= gain[h];
    Qo[(size_t)task * 64 + lane] = f2bf(y);
}

// ---------------- k prep (reads fused KV gemm output, cols=512) ----------------
__global__ __launch_bounds__(256) void k_prep_k(const float* __restrict__ Ckv,
                                                const float* __restrict__ rc,
                                                const float* __restrict__ rs,
                                                u16* __restrict__ Ko) {
    int lane = threadIdx.x & 63;
    int task = blockIdx.x * 4 + (threadIdx.x >> 6);  // (b*4+kv)*1024+s
    int s = task & 1023;
    int kv = (task >> 10) & 3;
    int b = task >> 12;
    float xv = Ckv[((size_t)b * 1024 + s) * 512 + kv * 64 + lane];
    float ss = xv * xv;
    #pragma unroll
    for (int off = 32; off; off >>= 1) ss += __shfl_xor(ss, off);
    float r = 1.0f / sqrtf(ss * (1.0f / 64.0f) + 1.1920929e-07f);
    xv *= r;
    float xp = __shfl_xor(xv, 32);
    int i = lane & 31;
    float c = rc[s * 32 + i], sn = rs[s * 32 + i];
    float y = (lane < 32) ? (xv * c + xp * sn) : (xv * c - xp * sn);
    Ko[(size_t)task * 64 + lane] = f2bf(y);
}

// ---------------- v transpose: Ckv [b,s,512] (+256 offset) -> Vt [b,kv,d,s] bf16 ----------------
__global__ __launch_bounds__(256) void k_vtransT(const float* __restrict__ Ckv,
                                                 u16* __restrict__ Vt) {
    __shared__ u16 T[64][72];
    int st = blockIdx.x, kv = blockIdx.y, b = blockIdx.z;
    int tid = threadIdx.x;
    int sr = tid >> 4, d4 = tid & 15;
    #pragma unroll
    for (int i = 0; i < 4; ++i) {
        int s = sr + 16 * i;
        float4 v = *reinterpret_cast<const float4*>(
            &Ckv[(size_t)(b * 1024 + st * 64 + s) * 512 + 256 + kv * 64 + d4 * 4]);
        T[d4 * 4 + 0][s] = f2bf(v.x);
        T[d4 * 4 + 1][s] = f2bf(v.y);
        T[d4 * 4 + 2][s] = f2bf(v.z);
        T[d4 * 4 + 3][s] = f2bf(v.w);
    }
    __syncthreads();
    int d = tid >> 2, c = tid & 3;
    float4 o0 = *reinterpret_cast<const float4*>(&T[d][c * 16]);
    float4 o1 = *reinterpret_cast<const float4*>(&T[d][c * 16 + 8]);
    u16* out = &Vt[(((size_t)(b * 4 + kv) * 64) + d) * 1024 + st * 64 + c * 16];
    *reinterpret_cast<float4*>(out) = o0;
    *reinterpret_cast<float4*>(out + 8) = o1;
}

// ---------------- causal flash attention, bf16 MFMA, paired q-tiles ----------------
// grid (8, 16, 8): block handles q-tiles qta=bx and qtb=15-bx (uniform 17 tiles).
// 4 waves, wave w owns q-rows [qt*64+16w,+16) of each tile.
// K/V double-buffered in LDS via global_load_lds, XOR-swizzled (slot ^= row&7)
// through pre-swizzled global source addresses (LDS dest stays linear).
__global__ __launch_bounds__(256) void k_attn_mfma(const u16* __restrict__ Q,
                                                   const u16* __restrict__ K,
                                                   const u16* __restrict__ Vt,
                                                   float* __restrict__ Y) {
    __shared__ u16 KVs[2][2][4096];   // [buf][K/V][64*64], swizzled layout
    __shared__ u16 Ps[4][16][72];     // per-wave P strip [q][key]
    int qta = blockIdx.x, qtb = 15 - qta;
    int h = blockIdx.y, b = blockIdx.z;
    int kvh = h >> 2;
    int tid = threadIdx.x;
    int w = tid >> 6, lane = tid & 63;
    int lr = lane & 15, lg = lane >> 4;
    int lr7 = lr & 7;
    int q0a = qta * 64 + w * 16, q0b = qtb * 64 + w * 16;
    const u16* Qb = Q + (((size_t)b * 16 + h) * 1024) * 64;
    const u16* Kb = K + (((size_t)b * 4 + kvh) * 1024) * 64;
    const u16* Vb = Vt + (((size_t)b * 4 + kvh) * 64) * 1024;

    bf16x8 qa0 = *reinterpret_cast<const bf16x8*>(&Qb[(size_t)(q0a + lr) * 64 + 8 * lg]);
    bf16x8 qa1 = *reinterpret_cast<const bf16x8*>(&Qb[(size_t)(q0a + lr) * 64 + 32 + 8 * lg]);
    bf16x8 qb0 = *reinterpret_cast<const bf16x8*>(&Qb[(size_t)(q0b + lr) * 64 + 8 * lg]);
    bf16x8 qb1 = *reinterpret_cast<const bf16x8*>(&Qb[(size_t)(q0b + lr) * 64 + 32 + 8 * lg]);

    float mA[4], lA[4], mB[4], lB[4];
    f32x4 accA[4], accB[4];
    #pragma unroll
    for (int r = 0; r < 4; ++r) { mA[r] = -INFINITY; lA[r] = 0.f; mB[r] = -INFINITY; lB[r] = 0.f; }
    #pragma unroll
    for (int dt = 0; dt < 4; ++dt) { accA[dt] = (f32x4){0.f,0.f,0.f,0.f}; accB[dt] = (f32x4){0.f,0.f,0.f,0.f}; }

    const float SC = 0.125f * 1.4426950408889634f;  // scale * log2(e)

    // staging: wave w stages chunks {2w, 2w+1} of K and of V.
    // chunk c covers rows 8c..8c+7; lane l -> row 8c+(l>>3), slot l&7 (linear dest);
    // source col16 pre-swizzled: col16 = (l&7) ^ (l>>3)  => LDS slot s holds col16 s^(row&7).
    int sub = lane >> 3, s7 = lane & 7;
    int scol16 = s7 ^ sub;   // 0..7
    int c0 = 2 * w, c1 = 2 * w + 1;

    #define STAGE(buf, t_) do { \
        int kk0 = (t_) * 64; \
        gload16(Kb + (size_t)(kk0 + 8 * c0 + sub) * 64 + scol16 * 8, &KVs[buf][0][c0 * 512]); \
        gload16(Kb + (size_t)(kk0 + 8 * c1 + sub) * 64 + scol16 * 8, &KVs[buf][0][c1 * 512]); \
        gload16(Vb + (size_t)(8 * c0 + sub) * 1024 + kk0 + scol16 * 8, &KVs[buf][1][c0 * 512]); \
        gload16(Vb + (size_t)(8 * c1 + sub) * 1024 + kk0 + scol16 * 8, &KVs[buf][1][c1 * 512]); \
    } while (0)

    STAGE(0, 0);
    asm volatile("s_waitcnt vmcnt(0)" ::: "memory");
    __syncthreads();
    int cur = 0;

    for (int t = 0; t <= qtb; ++t) {
        if (t < qtb) STAGE(cur ^ 1, t + 1);
        const int k0 = t * 64;
        const bool doA = (t <= qta);
        const u16* Kl = KVs[cur][0];
        const u16* Vl = KVs[cur][1];

        // ---- QK^T for both tiles (K-frags shared) ----
        float svA[4][4], svB[4][4];
        #pragma unroll
        for (int t4 = 0; t4 < 4; ++t4) {
            int r = t4 * 16 + lr;
            bf16x8 kf0 = *reinterpret_cast<const bf16x8*>(&Kl[r * 64 + ((lg ^ lr7) << 3)]);
            bf16x8 kf1 = *reinterpret_cast<const bf16x8*>(&Kl[r * 64 + (((4 | lg) ^ lr7) << 3)]);
            if (doA) {
                f32x4 z = (f32x4){0.f,0.f,0.f,0.f};
                z = __builtin_amdgcn_mfma_f32_16x16x32_bf16(qa0, kf0, z, 0, 0, 0);
                z = __builtin_amdgcn_mfma_f32_16x16x32_bf16(qa1, kf1, z, 0, 0, 0);
                #pragma unroll
                for (int rr = 0; rr < 4; ++rr) svA[t4][rr] = z[rr] * SC;
            }
            f32x4 z2 = (f32x4){0.f,0.f,0.f,0.f};
            z2 = __builtin_amdgcn_mfma_f32_16x16x32_bf16(qb0, kf0, z2, 0, 0, 0);
            z2 = __builtin_amdgcn_mfma_f32_16x16x32_bf16(qb1, kf1, z2, 0, 0, 0);
            #pragma unroll
            for (int rr = 0; rr < 4; ++rr) svB[t4][rr] = z2[rr] * SC;
        }
        if (doA && t == qta) {
            #pragma unroll
            for (int t4 = 0; t4 < 4; ++t4) {
                int key = k0 + t4 * 16 + lr;
                #pragma unroll
                for (int rr = 0; rr < 4; ++rr)
                    if (key > q0a + lg * 4 + rr) svA[t4][rr] = -3.0e38f;
            }
        }
        if (t == qtb) {
            #pragma unroll
            for (int t4 = 0; t4 < 4; ++t4) {
                int key = k0 + t4 * 16 + lr;
                #pragma unroll
                for (int rr = 0; rr < 4; ++rr)
                    if (key > q0b + lg * 4 + rr) svB[t4][rr] = -3.0e38f;
            }
        }

        // ---- online softmax A ----
        bf16x8 paA0, paA1, paB0, paB1;
        if (doA) {
            #pragma unroll
            for (int rr = 0; rr < 4; ++rr) {
                float mm = fmaxf(fmaxf(svA[0][rr], svA[1][rr]), fmaxf(svA[2][rr], svA[3][rr]));
                #pragma unroll
                for (int off = 8; off; off >>= 1) mm = fmaxf(mm, __shfl_xor(mm, off));
                float mn = fmaxf(mA[rr], mm);
                float corr = exp2f(mA[rr] - mn);
                mA[rr] = mn;
                float rsum = 0.f;
                float pp[4];
                #pragma unroll
                for (int t4 = 0; t4 < 4; ++t4) { pp[t4] = exp2f(svA[t4][rr] - mn); rsum += pp[t4]; }
                #pragma unroll
                for (int off = 8; off; off >>= 1) rsum += __shfl_xor(rsum, off);
                lA[rr] = lA[rr] * corr + rsum;
                #pragma unroll
                for (int dt = 0; dt < 4; ++dt) accA[dt][rr] *= corr;
                #pragma unroll
                for (int t4 = 0; t4 < 4; ++t4) Ps[w][lg * 4 + rr][t4 * 16 + lr] = f2bf(pp[t4]);
            }
            paA0 = *reinterpret_cast<const bf16x8*>(&Ps[w][lr][8 * lg]);
            paA1 = *reinterpret_cast<const bf16x8*>(&Ps[w][lr][32 + 8 * lg]);
        }

        // ---- online softmax B ----
        {
            #pragma unroll
            for (int rr = 0; rr < 4; ++rr) {
                float mm = fmaxf(fmaxf(svB[0][rr], svB[1][rr]), fmaxf(svB[2][rr], svB[3][rr]));
                #pragma unroll
                for (int off = 8; off; off >>= 1) mm = fmaxf(mm, __shfl_xor(mm, off));
                float mn = fmaxf(mB[rr], mm);
                float corr = exp2f(mB[rr] - mn);
                mB[rr] = mn;
                float rsum = 0.f;
                float pp[4];
                #pragma unroll
                for (int t4 = 0; t4 < 4; ++t4) { pp[t4] = exp2f(svB[t4][rr] - mn); rsum += pp[t4]; }
                #pragma unroll
                for (int off = 8; off; off >>= 1) rsum += __shfl_xor(rsum, off);
                lB[rr] = lB[rr] * corr + rsum;
                #pragma unroll
                for (int dt = 0; dt < 4; ++dt) accB[dt][rr] *= corr;
                #pragma unroll
                for (int t4 = 0; t4 < 4; ++t4) Ps[w][lg * 4 + rr][t4 * 16 + lr] = f2bf(pp[t4]);
            }
            paB0 = *reinterpret_cast<const bf16x8*>(&Ps[w][lr][8 * lg]);
            paB1 = *reinterpret_cast<const bf16x8*>(&Ps[w][lr][32 + 8 * lg]);
        }

        // ---- PV for both tiles (V-frags shared) ----
        #pragma unroll
        for (int dt = 0; dt < 4; ++dt) {
            int r = dt * 16 + lr;
            bf16x8 vf0 = *reinterpret_cast<const bf16x8*>(&Vl[r * 64 + ((lg ^ lr7) << 3)]);
            bf16x8 vf1 = *reinterpret_cast<const bf16x8*>(&Vl[r * 64 + (((4 | lg) ^ lr7) << 3)]);
            if (doA) {
                accA[dt] = __builtin_amdgcn_mfma_f32_16x16x32_bf16(paA0, vf0, accA[dt], 0, 0, 0);
                accA[dt] = __builtin_amdgcn_mfma_f32_16x16x32_bf16(paA1, vf1, accA[dt], 0, 0, 0);
            }
            accB[dt] = __builtin_amdgcn_mfma_f32_16x16x32_bf16(paB0, vf0, accB[dt], 0, 0, 0);
            accB[dt] = __builtin_amdgcn_mfma_f32_16x16x32_bf16(paB1, vf1, accB[dt], 0, 0, 0);
        }

        asm volatile("s_waitcnt vmcnt(0)" ::: "memory");
        __syncthreads();
        cur ^= 1;
    }
    #undef STAGE

    #pragma unroll
    for (int rr = 0; rr < 4; ++rr) {
        float invA = 1.0f / lA[rr];
        float invB = 1.0f / lB[rr];
        size_t baseA = ((size_t)(b * 1024 + q0a + lg * 4 + rr)) * 1024 + h * 64;
        size_t baseB = ((size_t)(b * 1024 + q0b + lg * 4 + rr)) * 1024 + h * 64;
        #pragma unroll
        for (int dt = 0; dt < 4; ++dt) {
            Y[baseA + dt * 16 + lr] = accA[dt][rr] * invA;
            Y[baseB + dt * 16 + lr] = accB[dt][rr] * invB;
        }
    }
}

extern "C" void kernel_launch(void* const* d_in, const int* in_sizes, int n_in,
                              void* d_out, int out_size, void* d_ws, size_t ws_size,
                              hipStream_t stream) {
    (void)in_sizes; (void)n_in; (void)out_size; (void)ws_size;
    const float* x  = (const float*)d_in[0];
    const float* Wq = (const float*)d_in[1];
    const float* Wk = (const float*)d_in[2];
    const float* Wv = (const float*)d_in[3];
    const float* Wp = (const float*)d_in[4];
    const float* qg = (const float*)d_in[5];
    float* out = (float*)d_out;

    float* p = (float*)d_ws;
    float* partial = p; p += 256;
    float* alpha = p;   p += 16;
    u16* wtq  = (u16*)p; p += 524288;   // 1M u16
    u16* wtkv = (u16*)p; p += 262144;   // 512K u16 (Wk rows 0..255, Wv rows 256..511)
    u16* wtp  = (u16*)p; p += 524288;   // 1M u16
    u16* xq   = (u16*)p; p += 4194304;  // 8M u16
    float* gam = p; p += 8192;
    float* cq  = p; p += 8388608;       // f32 [8192][1024]
    float* ckv = p; p += 4194304;       // f32 [8192][512]
    u16* qo = (u16*)p; p += 4194304;    // bf16 [b,h,s,64]
    u16* ko = (u16*)p; p += 1048576;    // bf16 [b,kv,s,64]
    u16* vt = (u16*)p; p += 1048576;    // bf16 [b,kv,64,s]
    float* rc = p; p += 32768;
    float* rs = p; p += 32768;
    float* y  = cq;        // reuse (cq dead after prep_q)
    u16*   yq = xq;        // reuse (xq dead after qkv gemms)

    // weight quantization
    k_absmean<<<64, 256, 0, stream>>>(Wq, 1048576, partial + 0);
    k_absmean<<<64, 256, 0, stream>>>(Wk, 262144, partial + 64);
    k_absmean<<<64, 256, 0, stream>>>(Wv, 262144, partial + 128);
    k_absmean<<<64, 256, 0, stream>>>(Wp, 1048576, partial + 192);
    k_alpha<<<1, 64, 0, stream>>>(partial, alpha);
    k_tern<<<512, 256, 0, stream>>>(Wq, alpha, 0, wtq, 262144);
    k_tern<<<128, 256, 0, stream>>>(Wk, alpha, 1, wtkv, 65536);
    k_tern<<<128, 256, 0, stream>>>(Wv, alpha, 2, wtkv + 262144, 65536);
    k_tern<<<512, 256, 0, stream>>>(Wp, alpha, 3, wtp, 262144);

    // rope table
    k_rope<<<128, 256, 0, stream>>>(rc, rs);

    // activation quantization + projections (bf16 MFMA, exact integer math)
    k_quant<<<ROWS, 256, 0, stream>>>(x, xq, gam);
    k_gemm_mfma<<<dim3(8, 64), 256, 0, stream>>>(xq, wtq, gam, alpha, 0, -1, cq, 1024);
    k_gemm_mfma<<<dim3(4, 64), 256, 0, stream>>>(xq, wtkv, gam, alpha, 1, 2, ckv, 512);

    // norm + rope + layout
    k_prep_q<<<32768, 256, 0, stream>>>(cq, rc, rs, qg, qo);
    k_prep_k<<<8192, 256, 0, stream>>>(ckv, rc, rs, ko);
    k_vtransT<<<dim3(16, 4, 8), 256, 0, stream>>>(ckv, vt);

    // attention (bf16 MFMA flash, paired causal tiles, async dbuf staging)
    k_attn_mfma<<<dim3(8, 16, 8), 256, 0, stream>>>(qo, ko, vt, y);

    // output projection
    k_quant<<<ROWS, 256, 0, stream>>>(y, yq, gam);
    k_gemm_mfma<<<dim3(8, 64), 256, 0, stream>>>(yq, wtp, gam, alpha, 3, -1, out, 1024);
}

// Round 5
// 269.672 us; speedup vs baseline: 6.8884x; 1.0869x over previous
//
#include <hip/hip_runtime.h>
#include <cmath>

#define DIMM 1024
#define NHEADS 16
#define NKV 4
#define HD 64
#define SEQ 1024
#define BSZ 8
#define ROWS (BSZ * SEQ)   // 8192

typedef unsigned short u16;
typedef __attribute__((ext_vector_type(8))) short bf16x8;
typedef __attribute__((ext_vector_type(4))) float f32x4;
typedef __attribute__((ext_vector_type(4))) unsigned short u16x4;

static __device__ __forceinline__ u16 f2bf(float f) {
    union { float f; unsigned u; } v; v.f = f;
    unsigned r = v.u + 0x7FFFu + ((v.u >> 16) & 1u);
    return (u16)(r >> 16);
}

// async global->LDS, 16B per lane; dst must be wave-uniform base (HW adds lane*16)
static __device__ __forceinline__ void gload16(const u16* g, u16* l) {
    __builtin_amdgcn_global_load_lds(
        (const __attribute__((address_space(1))) unsigned int*)g,
        (__attribute__((address_space(3))) unsigned int*)l, 16, 0, 0);
}

// ---------------- weight abs-mean partial reduce ----------------
__global__ __launch_bounds__(256) void k_absmean(const float* __restrict__ w, int n,
                                                 float* __restrict__ partial) {
    float s = 0.f;
    for (int i = blockIdx.x * 256 + threadIdx.x; i < n; i += 64 * 256) s += fabsf(w[i]);
    #pragma unroll
    for (int off = 32; off; off >>= 1) s += __shfl_xor(s, off);
    __shared__ float red[4];
    if ((threadIdx.x & 63) == 0) red[threadIdx.x >> 6] = s;
    __syncthreads();
    if (threadIdx.x == 0) partial[blockIdx.x] = red[0] + red[1] + red[2] + red[3];
}

// ---------------- alpha = max(mean|w|, eps) ----------------
__global__ void k_alpha(const float* __restrict__ partial, float* __restrict__ alpha) {
    int i = threadIdx.x;
    if (i < 4) {
        const int ns[4] = {1048576, 262144, 262144, 1048576};
        float s = 0.f;
        for (int j = 0; j < 64; ++j) s += partial[i * 64 + j];
        alpha[i] = fmaxf(s / (float)ns[i], 1e-8f);
    }
}

// ---------------- ternarize -> bf16 (values {-1,0,1}, exact) ----------------
__global__ __launch_bounds__(256) void k_tern(const float* __restrict__ w,
                                              const float* __restrict__ alpha, int ai,
                                              u16* __restrict__ wt, int n4) {
    float a = alpha[ai];
    for (int i = blockIdx.x * blockDim.x + threadIdx.x; i < n4; i += gridDim.x * blockDim.x) {
        float4 v = *reinterpret_cast<const float4*>(&w[i * 4]);
        u16x4 o;
        o.x = f2bf(rintf(fminf(fmaxf(v.x / a, -1.f), 1.f)));
        o.y = f2bf(rintf(fminf(fmaxf(v.y / a, -1.f), 1.f)));
        o.z = f2bf(rintf(fminf(fmaxf(v.z / a, -1.f), 1.f)));
        o.w = f2bf(rintf(fminf(fmaxf(v.w / a, -1.f), 1.f)));
        *reinterpret_cast<u16x4*>(&wt[i * 4]) = o;
    }
}

// ---------------- per-row activation quantization -> bf16 ints ----------------
__global__ __launch_bounds__(256) void k_quant(const float* __restrict__ X,
                                               u16* __restrict__ Xq, float* __restrict__ g) {
    int row = blockIdx.x;
    const float* xr = X + (size_t)row * DIMM;
    float4 v = *reinterpret_cast<const float4*>(&xr[threadIdx.x * 4]);
    float mv = fmaxf(fmaxf(fabsf(v.x), fabsf(v.y)), fmaxf(fabsf(v.z), fabsf(v.w)));
    #pragma unroll
    for (int off = 32; off; off >>= 1) mv = fmaxf(mv, __shfl_xor(mv, off));
    __shared__ float red[4];
    if ((threadIdx.x & 63) == 0) red[threadIdx.x >> 6] = mv;
    __syncthreads();
    mv = fmaxf(fmaxf(red[0], red[1]), fmaxf(red[2], red[3]));
    float gamma = fmaxf(mv, 1e-8f) / 127.0f;
    u16x4 o;
    o.x = f2bf(rintf(fminf(fmaxf(v.x / gamma, -128.f), 127.f)));
    o.y = f2bf(rintf(fminf(fmaxf(v.y / gamma, -128.f), 127.f)));
    o.z = f2bf(rintf(fminf(fmaxf(v.z / gamma, -128.f), 127.f)));
    o.w = f2bf(rintf(fminf(fmaxf(v.w / gamma, -128.f), 127.f)));
    *reinterpret_cast<u16x4*>(&Xq[(size_t)row * DIMM + threadIdx.x * 4]) = o;
    if (threadIdx.x == 0) g[row] = gamma;
}

// ---------------- bf16 MFMA GEMM (m97 structure + XOR-swizzled LDS) ----------------
// Swizzle: staging window = 8 rows x 8 slots(16B); lane l -> row l>>3, src slot (l&7)^(l>>3)
// (LDS dest linear); read slot s of row r lives at slot s^(r&7) -> conflict-free b128 reads.
__global__ __launch_bounds__(256) void k_gemm_mfma(const u16* __restrict__ A,
                                                   const u16* __restrict__ B,
                                                   const float* __restrict__ gamma,
                                                   const float* __restrict__ alpha_p, int ai, int ai2,
                                                   float* __restrict__ C, int cols) {
    __shared__ u16 As[128 * 64];
    __shared__ u16 Bs[128 * 64];
    const int K = DIMM;
    int tid = threadIdx.x;
    int w = tid >> 6, lane = tid & 63;
    int lr = lane & 15, lg = lane >> 4;
    int lr7 = lr & 7;
    int wm = w >> 1, wn = w & 1;
    int row0 = blockIdx.y * 128, col0 = blockIdx.x * 128;

    f32x4 acc[4][4];
    #pragma unroll
    for (int mf = 0; mf < 4; ++mf)
        #pragma unroll
        for (int nf = 0; nf < 4; ++nf) acc[mf][nf] = (f32x4){0.f, 0.f, 0.f, 0.f};

    int srow = w * 32 + (lane >> 3);
    int scol = 8 * ((lane & 7) ^ (lane >> 3));   // pre-swizzled source slot
    const u16* Ag = A + (size_t)(row0 + srow) * K + scol;
    const u16* Bg = B + (size_t)(col0 + srow) * K + scol;

    for (int k0 = 0; k0 < K; k0 += 64) {
        #pragma unroll
        for (int i = 0; i < 4; ++i) {
            gload16(Ag + (size_t)i * 8 * K + k0, &As[w * 2048 + i * 512]);
            gload16(Bg + (size_t)i * 8 * K + k0, &Bs[w * 2048 + i * 512]);
        }
        __syncthreads();
        #pragma unroll
        for (int kk = 0; kk < 64; kk += 32) {
            int sl = (kk >> 3);   // 0 or 4
            bf16x8 af[4], bfr[4];
            #pragma unroll
            for (int mf = 0; mf < 4; ++mf)
                af[mf] = *reinterpret_cast<const bf16x8*>(
                    &As[(wm * 64 + mf * 16 + lr) * 64 + 8 * ((sl + lg) ^ lr7)]);
            #pragma unroll
            for (int nf = 0; nf < 4; ++nf)
                bfr[nf] = *reinterpret_cast<const bf16x8*>(
                    &Bs[(wn * 64 + nf * 16 + lr) * 64 + 8 * ((sl + lg) ^ lr7)]);
            #pragma unroll
            for (int mf = 0; mf < 4; ++mf)
                #pragma unroll
                for (int nf = 0; nf < 4; ++nf)
                    acc[mf][nf] = __builtin_amdgcn_mfma_f32_16x16x32_bf16(af[mf], bfr[nf], acc[mf][nf], 0, 0, 0);
        }
        __syncthreads();
    }

    int a_idx = (ai2 >= 0 && col0 >= 256) ? ai2 : ai;
    float alpha = alpha_p[a_idx];
    #pragma unroll
    for (int mf = 0; mf < 4; ++mf) {
        #pragma unroll
        for (int reg = 0; reg < 4; ++reg) {
            int row = row0 + wm * 64 + mf * 16 + lg * 4 + reg;
            float sc = gamma[row] * alpha;
            #pragma unroll
            for (int nf = 0; nf < 4; ++nf)
                C[(size_t)row * cols + col0 + wn * 64 + nf * 16 + lr] = acc[mf][nf][reg] * sc;
        }
    }
}

// ---------------- rope table ----------------
__global__ __launch_bounds__(256) void k_rope(float* __restrict__ c, float* __restrict__ s) {
    int idx = blockIdx.x * 256 + threadIdx.x;  // < 32768
    int t = idx >> 5, i = idx & 31;
    float inv = 1.0f / powf(10000.0f, (float)(2 * i) * (1.0f / 64.0f));
    float f = (float)t * inv;
    c[idx] = cosf(f);
    s[idx] = sinf(f);
}

// ---------------- q prep: rms_norm + rope + gain (+score scale folded) -> bf16 ----------------
__global__ __launch_bounds__(256) void k_prep_q(const float* __restrict__ C,
                                                const float* __restrict__ rc,
                                                const float* __restrict__ rs,
                                                const float* __restrict__ gain,
                                                u16* __restrict__ Qo) {
    int lane = threadIdx.x & 63;
    int task = blockIdx.x * 4 + (threadIdx.x >> 6);  // (b*16+h)*1024+s
    int s = task & 1023;
    int h = (task >> 10) & 15;
    int b = task >> 14;
    float xv = C[(((size_t)b * 1024 + s) * 16 + h) * 64 + lane];
    float ss = xv * xv;
    #pragma unroll
    for (int off = 32; off; off >>= 1) ss += __shfl_xor(ss, off);
    float r = 1.0f / sqrtf(ss * (1.0f / 64.0f) + 1.1920929e-07f);
    xv *= r;
    float xp = __shfl_xor(xv, 32);
    int i = lane & 31;
    float c = rc[s * 32 + i], sn = rs[s * 32 + i];
    float y = (lane < 32) ? (xv * c + xp * sn) : (xv * c - xp * sn);
    y *= gain[h] * (0.125f * 1.4426950408889634f);   // fold scale*log2(e) into Q
    Qo[(size_t)task * 64 + lane] = f2bf(y);
}

// ---------------- k prep (reads fused KV gemm output, cols=512) ----------------
__global__ __launch_bounds__(256) void k_prep_k(const float* __restrict__ Ckv,
                                                const float* __restrict__ rc,
                                                const float* __restrict__ rs,
                                                u16* __restrict__ Ko) {
    int lane = threadIdx.x & 63;
    int task = blockIdx.x * 4 + (threadIdx.x >> 6);  // (b*4+kv)*1024+s
    int s = task & 1023;
    int kv = (task >> 10) & 3;
    int b = task >> 12;
    float xv = Ckv[((size_t)b * 1024 + s) * 512 + kv * 64 + lane];
    float ss = xv * xv;
    #pragma unroll
    for (int off = 32; off; off >>= 1) ss += __shfl_xor(ss, off);
    float r = 1.0f / sqrtf(ss * (1.0f / 64.0f) + 1.1920929e-07f);
    xv *= r;
    float xp = __shfl_xor(xv, 32);
    int i = lane & 31;
    float c = rc[s * 32 + i], sn = rs[s * 32 + i];
    float y = (lane < 32) ? (xv * c + xp * sn) : (xv * c - xp * sn);
    Ko[(size_t)task * 64 + lane] = f2bf(y);
}

// ---------------- v transpose: Ckv [b,s,512] (+256 offset) -> Vt [b,kv,d,s] bf16 ----------------
__global__ __launch_bounds__(256) void k_vtransT(const float* __restrict__ Ckv,
                                                 u16* __restrict__ Vt) {
    __shared__ u16 T[64][72];
    int st = blockIdx.x, kv = blockIdx.y, b = blockIdx.z;
    int tid = threadIdx.x;
    int sr = tid >> 4, d4 = tid & 15;
    #pragma unroll
    for (int i = 0; i < 4; ++i) {
        int s = sr + 16 * i;
        float4 v = *reinterpret_cast<const float4*>(
            &Ckv[(size_t)(b * 1024 + st * 64 + s) * 512 + 256 + kv * 64 + d4 * 4]);
        T[d4 * 4 + 0][s] = f2bf(v.x);
        T[d4 * 4 + 1][s] = f2bf(v.y);
        T[d4 * 4 + 2][s] = f2bf(v.z);
        T[d4 * 4 + 3][s] = f2bf(v.w);
    }
    __syncthreads();
    int d = tid >> 2, c = tid & 3;
    float4 o0 = *reinterpret_cast<const float4*>(&T[d][c * 16]);
    float4 o1 = *reinterpret_cast<const float4*>(&T[d][c * 16 + 8]);
    u16* out = &Vt[(((size_t)(b * 4 + kv) * 64) + d) * 1024 + st * 64 + c * 16];
    *reinterpret_cast<float4*>(out) = o0;
    *reinterpret_cast<float4*>(out + 8) = o1;
}

// ---------------- causal flash attention, bf16 MFMA, paired q-tiles ----------------
// grid (8, 16, 8): block handles q-tiles qta=bx and qtb=15-bx (uniform 17 tiles).
// Defer-max (THR=8, log2 domain) + deferred per-lane denominator partials.
__global__ __launch_bounds__(256) void k_attn_mfma(const u16* __restrict__ Q,
                                                   const u16* __restrict__ K,
                                                   const u16* __restrict__ Vt,
                                                   float* __restrict__ Y) {
    __shared__ u16 KVs[2][2][4096];   // [buf][K/V][64*64], swizzled layout
    __shared__ u16 Ps[4][16][72];     // per-wave P strip [q][key]
    int qta = blockIdx.x, qtb = 15 - qta;
    int h = blockIdx.y, b = blockIdx.z;
    int kvh = h >> 2;
    int tid = threadIdx.x;
    int w = tid >> 6, lane = tid & 63;
    int lr = lane & 15, lg = lane >> 4;
    int lr7 = lr & 7;
    int q0a = qta * 64 + w * 16, q0b = qtb * 64 + w * 16;
    const u16* Qb = Q + (((size_t)b * 16 + h) * 1024) * 64;
    const u16* Kb = K + (((size_t)b * 4 + kvh) * 1024) * 64;
    const u16* Vb = Vt + (((size_t)b * 4 + kvh) * 64) * 1024;

    bf16x8 qa0 = *reinterpret_cast<const bf16x8*>(&Qb[(size_t)(q0a + lr) * 64 + 8 * lg]);
    bf16x8 qa1 = *reinterpret_cast<const bf16x8*>(&Qb[(size_t)(q0a + lr) * 64 + 32 + 8 * lg]);
    bf16x8 qb0 = *reinterpret_cast<const bf16x8*>(&Qb[(size_t)(q0b + lr) * 64 + 8 * lg]);
    bf16x8 qb1 = *reinterpret_cast<const bf16x8*>(&Qb[(size_t)(q0b + lr) * 64 + 32 + 8 * lg]);

    float mA[4], lpA[4], mB[4], lpB[4];   // lp = per-lane denominator partial
    f32x4 accA[4], accB[4];
    #pragma unroll
    for (int r = 0; r < 4; ++r) { mA[r] = -INFINITY; lpA[r] = 0.f; mB[r] = -INFINITY; lpB[r] = 0.f; }
    #pragma unroll
    for (int dt = 0; dt < 4; ++dt) { accA[dt] = (f32x4){0.f,0.f,0.f,0.f}; accB[dt] = (f32x4){0.f,0.f,0.f,0.f}; }

    int sub = lane >> 3, s7 = lane & 7;
    int scol16 = s7 ^ sub;
    int c0 = 2 * w, c1 = 2 * w + 1;

    #define STAGE(buf, t_) do { \
        int kk0 = (t_) * 64; \
        gload16(Kb + (size_t)(kk0 + 8 * c0 + sub) * 64 + scol16 * 8, &KVs[buf][0][c0 * 512]); \
        gload16(Kb + (size_t)(kk0 + 8 * c1 + sub) * 64 + scol16 * 8, &KVs[buf][0][c1 * 512]); \
        gload16(Vb + (size_t)(8 * c0 + sub) * 1024 + kk0 + scol16 * 8, &KVs[buf][1][c0 * 512]); \
        gload16(Vb + (size_t)(8 * c1 + sub) * 1024 + kk0 + scol16 * 8, &KVs[buf][1][c1 * 512]); \
    } while (0)

    STAGE(0, 0);
    asm volatile("s_waitcnt vmcnt(0)" ::: "memory");
    __syncthreads();
    int cur = 0;

    for (int t = 0; t <= qtb; ++t) {
        if (t < qtb) STAGE(cur ^ 1, t + 1);
        const int k0 = t * 64;
        const bool doA = (t <= qta);
        const u16* Kl = KVs[cur][0];
        const u16* Vl = KVs[cur][1];

        // ---- QK^T for both tiles (K-frags shared) ----
        float svA[4][4], svB[4][4];
        #pragma unroll
        for (int t4 = 0; t4 < 4; ++t4) {
            int r = t4 * 16 + lr;
            bf16x8 kf0 = *reinterpret_cast<const bf16x8*>(&Kl[r * 64 + ((lg ^ lr7) << 3)]);
            bf16x8 kf1 = *reinterpret_cast<const bf16x8*>(&Kl[r * 64 + (((4 | lg) ^ lr7) << 3)]);
            if (doA) {
                f32x4 z = (f32x4){0.f,0.f,0.f,0.f};
                z = __builtin_amdgcn_mfma_f32_16x16x32_bf16(qa0, kf0, z, 0, 0, 0);
                z = __builtin_amdgcn_mfma_f32_16x16x32_bf16(qa1, kf1, z, 0, 0, 0);
                #pragma unroll
                for (int rr = 0; rr < 4; ++rr) svA[t4][rr] = z[rr];
            }
            f32x4 z2 = (f32x4){0.f,0.f,0.f,0.f};
            z2 = __builtin_amdgcn_mfma_f32_16x16x32_bf16(qb0, kf0, z2, 0, 0, 0);
            z2 = __builtin_amdgcn_mfma_f32_16x16x32_bf16(qb1, kf1, z2, 0, 0, 0);
            #pragma unroll
            for (int rr = 0; rr < 4; ++rr) svB[t4][rr] = z2[rr];
        }
        if (doA && t == qta) {
            #pragma unroll
            for (int t4 = 0; t4 < 4; ++t4) {
                int key = k0 + t4 * 16 + lr;
                #pragma unroll
                for (int rr = 0; rr < 4; ++rr)
                    if (key > q0a + lg * 4 + rr) svA[t4][rr] = -3.0e38f;
            }
        }
        if (t == qtb) {
            #pragma unroll
            for (int t4 = 0; t4 < 4; ++t4) {
                int key = k0 + t4 * 16 + lr;
                #pragma unroll
                for (int rr = 0; rr < 4; ++rr)
                    if (key > q0b + lg * 4 + rr) svB[t4][rr] = -3.0e38f;
            }
        }

        // ---- softmax A (defer-max) ----
        bf16x8 paA0, paA1, paB0, paB1;
        if (doA) {
            float vx[4]; int ok = 1;
            #pragma unroll
            for (int rr = 0; rr < 4; ++rr) {
                vx[rr] = fmaxf(fmaxf(svA[0][rr], svA[1][rr]), fmaxf(svA[2][rr], svA[3][rr]));
                ok &= (vx[rr] <= mA[rr] + 8.0f);
            }
            if (!__all(ok)) {
                #pragma unroll
                for (int rr = 0; rr < 4; ++rr) {
                    float mm = vx[rr];
                    #pragma unroll
                    for (int off = 8; off; off >>= 1) mm = fmaxf(mm, __shfl_xor(mm, off));
                    float mn = fmaxf(mA[rr], mm);
                    float corr = exp2f(mA[rr] - mn);
                    mA[rr] = mn;
                    lpA[rr] *= corr;
                    #pragma unroll
                    for (int dt = 0; dt < 4; ++dt) accA[dt][rr] *= corr;
                }
            }
            #pragma unroll
            for (int rr = 0; rr < 4; ++rr)
                #pragma unroll
                for (int t4 = 0; t4 < 4; ++t4) {
                    float pp = exp2f(svA[t4][rr] - mA[rr]);
                    lpA[rr] += pp;
                    Ps[w][lg * 4 + rr][t4 * 16 + lr] = f2bf(pp);
                }
            paA0 = *reinterpret_cast<const bf16x8*>(&Ps[w][lr][8 * lg]);
            paA1 = *reinterpret_cast<const bf16x8*>(&Ps[w][lr][32 + 8 * lg]);
        }

        // ---- softmax B (defer-max) ----
        {
            float vx[4]; int ok = 1;
            #pragma unroll
            for (int rr = 0; rr < 4; ++rr) {
                vx[rr] = fmaxf(fmaxf(svB[0][rr], svB[1][rr]), fmaxf(svB[2][rr], svB[3][rr]));
                ok &= (vx[rr] <= mB[rr] + 8.0f);
            }
            if (!__all(ok)) {
                #pragma unroll
                for (int rr = 0; rr < 4; ++rr) {
                    float mm = vx[rr];
                    #pragma unroll
                    for (int off = 8; off; off >>= 1) mm = fmaxf(mm, __shfl_xor(mm, off));
                    float mn = fmaxf(mB[rr], mm);
                    float corr = exp2f(mB[rr] - mn);
                    mB[rr] = mn;
                    lpB[rr] *= corr;
                    #pragma unroll
                    for (int dt = 0; dt < 4; ++dt) accB[dt][rr] *= corr;
                }
            }
            #pragma unroll
            for (int rr = 0; rr < 4; ++rr)
                #pragma unroll
                for (int t4 = 0; t4 < 4; ++t4) {
                    float pp = exp2f(svB[t4][rr] - mB[rr]);
                    lpB[rr] += pp;
                    Ps[w][lg * 4 + rr][t4 * 16 + lr] = f2bf(pp);
                }
            paB0 = *reinterpret_cast<const bf16x8*>(&Ps[w][lr][8 * lg]);
            paB1 = *reinterpret_cast<const bf16x8*>(&Ps[w][lr][32 + 8 * lg]);
        }

        // ---- PV for both tiles (V-frags shared) ----
        #pragma unroll
        for (int dt = 0; dt < 4; ++dt) {
            int r = dt * 16 + lr;
            bf16x8 vf0 = *reinterpret_cast<const bf16x8*>(&Vl[r * 64 + ((lg ^ lr7) << 3)]);
            bf16x8 vf1 = *reinterpret_cast<const bf16x8*>(&Vl[r * 64 + (((4 | lg) ^ lr7) << 3)]);
            if (doA) {
                accA[dt] = __builtin_amdgcn_mfma_f32_16x16x32_bf16(paA0, vf0, accA[dt], 0, 0, 0);
                accA[dt] = __builtin_amdgcn_mfma_f32_16x16x32_bf16(paA1, vf1, accA[dt], 0, 0, 0);
            }
            accB[dt] = __builtin_amdgcn_mfma_f32_16x16x32_bf16(paB0, vf0, accB[dt], 0, 0, 0);
            accB[dt] = __builtin_amdgcn_mfma_f32_16x16x32_bf16(paB1, vf1, accB[dt], 0, 0, 0);
        }

        asm volatile("s_waitcnt vmcnt(0)" ::: "memory");
        __syncthreads();
        cur ^= 1;
    }
    #undef STAGE

    // final denominator reduce (deferred)
    #pragma unroll
    for (int rr = 0; rr < 4; ++rr) {
        #pragma unroll
        for (int off = 8; off; off >>= 1) {
            lpA[rr] += __shfl_xor(lpA[rr], off);
            lpB[rr] += __shfl_xor(lpB[rr], off);
        }
    }

    #pragma unroll
    for (int rr = 0; rr < 4; ++rr) {
        float invA = 1.0f / lpA[rr];
        float invB = 1.0f / lpB[rr];
        size_t baseA = ((size_t)(b * 1024 + q0a + lg * 4 + rr)) * 1024 + h * 64;
        size_t baseB = ((size_t)(b * 1024 + q0b + lg * 4 + rr)) * 1024 + h * 64;
        #pragma unroll
        for (int dt = 0; dt < 4; ++dt) {
            Y[baseA + dt * 16 + lr] = accA[dt][rr] * invA;
            Y[baseB + dt * 16 + lr] = accB[dt][rr] * invB;
        }
    }
}

extern "C" void kernel_launch(void* const* d_in, const int* in_sizes, int n_in,
                              void* d_out, int out_size, void* d_ws, size_t ws_size,
                              hipStream_t stream) {
    (void)in_sizes; (void)n_in; (void)out_size; (void)ws_size;
    const float* x  = (const float*)d_in[0];
    const float* Wq = (const float*)d_in[1];
    const float* Wk = (const float*)d_in[2];
    const float* Wv = (const float*)d_in[3];
    const float* Wp = (const float*)d_in[4];
    const float* qg = (const float*)d_in[5];
    float* out = (float*)d_out;

    float* p = (float*)d_ws;
    float* partial = p; p += 256;
    float* alpha = p;   p += 16;
    u16* wtq  = (u16*)p; p += 524288;   // 1M u16
    u16* wtkv = (u16*)p; p += 262144;   // 512K u16 (Wk rows 0..255, Wv rows 256..511)
    u16* wtp  = (u16*)p; p += 524288;   // 1M u16
    u16* xq   = (u16*)p; p += 4194304;  // 8M u16
    float* gam = p; p += 8192;
    float* cq  = p; p += 8388608;       // f32 [8192][1024]
    float* ckv = p; p += 4194304;       // f32 [8192][512]
    u16* qo = (u16*)p; p += 4194304;    // bf16 [b,h,s,64]
    u16* ko = (u16*)p; p += 1048576;    // bf16 [b,kv,s,64]
    u16* vt = (u16*)p; p += 1048576;    // bf16 [b,kv,64,s]
    float* rc = p; p += 32768;
    float* rs = p; p += 32768;
    float* y  = cq;        // reuse (cq dead after prep_q)
    u16*   yq = xq;        // reuse (xq dead after qkv gemms)

    // weight quantization
    k_absmean<<<64, 256, 0, stream>>>(Wq, 1048576, partial + 0);
    k_absmean<<<64, 256, 0, stream>>>(Wk, 262144, partial + 64);
    k_absmean<<<64, 256, 0, stream>>>(Wv, 262144, partial + 128);
    k_absmean<<<64, 256, 0, stream>>>(Wp, 1048576, partial + 192);
    k_alpha<<<1, 64, 0, stream>>>(partial, alpha);
    k_tern<<<512, 256, 0, stream>>>(Wq, alpha, 0, wtq, 262144);
    k_tern<<<128, 256, 0, stream>>>(Wk, alpha, 1, wtkv, 65536);
    k_tern<<<128, 256, 0, stream>>>(Wv, alpha, 2, wtkv + 262144, 65536);
    k_tern<<<512, 256, 0, stream>>>(Wp, alpha, 3, wtp, 262144);

    // rope table
    k_rope<<<128, 256, 0, stream>>>(rc, rs);

    // activation quantization + projections (bf16 MFMA, exact integer math)
    k_quant<<<ROWS, 256, 0, stream>>>(x, xq, gam);
    k_gemm_mfma<<<dim3(8, 64), 256, 0, stream>>>(xq, wtq, gam, alpha, 0, -1, cq, 1024);
    k_gemm_mfma<<<dim3(4, 64), 256, 0, stream>>>(xq, wtkv, gam, alpha, 1, 2, ckv, 512);

    // norm + rope + layout
    k_prep_q<<<32768, 256, 0, stream>>>(cq, rc, rs, qg, qo);
    k_prep_k<<<8192, 256, 0, stream>>>(ckv, rc, rs, ko);
    k_vtransT<<<dim3(16, 4, 8), 256, 0, stream>>>(ckv, vt);

    // attention (bf16 MFMA flash, paired causal tiles, defer-max softmax)
    k_attn_mfma<<<dim3(8, 16, 8), 256, 0, stream>>>(qo, ko, vt, y);

    // output projection
    k_quant<<<ROWS, 256, 0, stream>>>(y, yq, gam);
    k_gemm_mfma<<<dim3(8, 64), 256, 0, stream>>>(yq, wtp, gam, alpha, 3, -1, out, 1024);
}